// Round 9
// baseline (394.438 us; speedup 1.0000x reference)
//
#include <hip/hip_runtime.h>
#include <hip/hip_bf16.h>
#include <math.h>

#define NN 16384       // nodes
#define EE 131072      // edges
#define FIN 16
#define HID 128
#define NEG_SLOPE 0.2f

typedef float  floatx4 __attribute__((ext_vector_type(4)));
typedef short  shortx8 __attribute__((ext_vector_type(8)));

// fp32 -> bf16 RNE split helpers (hi catches top 8 mantissa bits, lo the next 8)
__device__ inline unsigned bf_hi_bits(float x) {
    unsigned u = __float_as_uint(x);
    return (u + 0x7FFFu + ((u >> 16) & 1u)) >> 16;
}

// ---------------------------------------------------------------------------
// CSR build
// ---------------------------------------------------------------------------
__global__ void count_kernel(const int* __restrict__ dst, int* __restrict__ deg) {
    int e = blockIdx.x * 256 + threadIdx.x;
    atomicAdd(&deg[dst[e]], 1);
}

__global__ __launch_bounds__(1024) void scan_kernel(int* __restrict__ degw /* in: deg, out: offsets */,
                                                    int* __restrict__ ptr) {
    __shared__ int sums[1024];
    int t = threadIdx.x;
    int base = t * 16;
    int local[16];
    int s = 0;
#pragma unroll
    for (int i = 0; i < 16; i++) { local[i] = degw[base + i]; s += local[i]; }
    sums[t] = s;
    __syncthreads();
    for (int off = 1; off < 1024; off <<= 1) {
        int v = (t >= off) ? sums[t - off] : 0;
        __syncthreads();
        sums[t] += v;
        __syncthreads();
    }
    int ex = (t == 0) ? 0 : sums[t - 1];
#pragma unroll
    for (int i = 0; i < 16; i++) {
        ptr[base + i] = ex;
        degw[base + i] = ex;   // working copy for scatter
        ex += local[i];
    }
    if (t == 1023) ptr[NN] = sums[1023];
}

__global__ void scatter_kernel(const int* __restrict__ src, const int* __restrict__ dst,
                               int* __restrict__ ptrw, int* __restrict__ csr_src) {
    int e = blockIdx.x * 256 + threadIdx.x;
    int p = atomicAdd(&ptrw[dst[e]], 1);
    csr_src[p] = src[e];
}

// ---------------------------------------------------------------------------
// Weight pre-split into MFMA B-fragment layout, once per call.
// mat: 0=Wl[0], 1=Wr[0], 2=Wl[1], 3=Wr[1], 4=Wh1. For mfma_f32_16x16x32_bf16,
// B-frag: lane l supplies B[k=(l>>4)*8+j][col=l&15] for j=0..7. Stored so one
// lane's 8 bf16 are contiguous: idx = ((mat*32 + ct*4 + kt)*64 + l)*8 + j.
// ---------------------------------------------------------------------------
__global__ void wsplit_kernel(const float* __restrict__ Wl, const float* __restrict__ Wr,
                              const float* __restrict__ Wh1,
                              unsigned short* __restrict__ hi, unsigned short* __restrict__ lo) {
    int mat = blockIdx.y;
    const float* W = (mat == 0) ? Wl : (mat == 1) ? Wr : (mat == 2) ? Wl + HID * HID
                   : (mat == 3) ? Wr + HID * HID : Wh1;
    int ct = blockIdx.x;             // col tile 0..7
    int t = threadIdx.x;
    int kt = t >> 6, l = t & 63;
    long obase = (((long)mat * 32 + (ct * 4 + kt)) * 64 + l) * 8;
    int c = ct * 16 + (l & 15);
    int kbase = kt * 32 + ((l >> 4) << 3);
#pragma unroll
    for (int j = 0; j < 8; j++) {
        float x = W[(kbase + j) * HID + c];
        unsigned hb = bf_hi_bits(x);
        float r = x - __uint_as_float(hb << 16);
        unsigned lb = bf_hi_bits(r);
        hi[obase + j] = (unsigned short)hb;
        lo[obase + j] = (unsigned short)lb;
    }
}

// ---------------------------------------------------------------------------
// Layer 0 linear. r8: the fused (hl,hr,hres) version held 96 weight-float2s
// in registers -> 176 VGPR -> 2 waves/SIMD -> 8% occupancy -> write-BW
// starved (2.15 TB/s on a 96 MB write stream). Now blockIdx.y picks ONE of
// the three matrices: 32 weight VGPRs, __launch_bounds__(256,4) -> 4
// waves/SIMD. x is 1 MB and L2-resident, so the 3x redundant x reads are free.
// ---------------------------------------------------------------------------
#define L0_BLOCKS 2048
__global__ __launch_bounds__(256, 4) void l0_kernel(const float* __restrict__ x,
                                                    const float* __restrict__ W0l,
                                                    const float* __restrict__ W0r,
                                                    const float* __restrict__ Wres,
                                                    float* __restrict__ hl,
                                                    float* __restrict__ hr,
                                                    float* __restrict__ hres,
                                                    int viewBase, long totalRows) {
    int tid = threadIdx.x;
    int my = blockIdx.y;
    const float* W = (my == 0) ? W0l : (my == 1) ? W0r : Wres;
    float* outp    = (my == 0) ? hl  : (my == 1) ? hr  : hres;
    int c2 = (tid & 63) * 2;
    float2 w2[FIN];
#pragma unroll
    for (int k = 0; k < FIN; k++) w2[k] = *(const float2*)(W + k * HID + c2);

    for (long lw = (long)blockIdx.x * 4 + (tid >> 6); lw < totalRows;
         lw += (long)L0_BLOCKS * 4) {
        int v = viewBase + (int)(lw >> 14);            // absolute view
        int n = (int)(lw & (NN - 1));                  // node
        const float* xr = x + (long)n * FIN;
        float a0 = 0.f, a1 = 0.f;
#pragma unroll
        for (int k = 0; k < FIN; k++) {
            float xk = xr[k];                          // wave-uniform
            if (k == 0 && (v & 1)) xk = -xk;           // flip x for views 1,3
            if (k == 1 && (v & 2)) xk = -xk;           // flip y for views 2,3
            a0 += xk * w2[k].x;
            a1 += xk * w2[k].y;
        }
        *(float2*)(outp + lw * HID + c2) = make_float2(a0, a1);
    }
}

// ---------------------------------------------------------------------------
// GATv2 edge attention + aggregate + residual + (optional) ELU.
// Wave = 4 edge-slots x 16 lanes, 8 dims/lane; head-dot reduce = 2 shuffles
// over a 4-lane group; slots run independent online softmax over an
// interleaved quarter of the edge list; one cross-slot merge per node.
// XCD swizzle: graph-view chunk pinned to one XCD (L2-resident working set).
// hout may alias hr or res (row-local reads before the only write).
// ---------------------------------------------------------------------------
__global__ __launch_bounds__(256) void attn_kernel(const float* __restrict__ hl,
                                                   const float* __restrict__ hr,
                                                   const float* __restrict__ res,
                                                   const int* __restrict__ ptr,
                                                   const int* __restrict__ csr_src,
                                                   const float* __restrict__ avec,
                                                   float* __restrict__ hout,
                                                   int act,
                                                   int gvPerXcd) {
    int xcd = blockIdx.x & 7;
    int slotb = blockIdx.x >> 3;
    int gv = xcd * gvPerXcd + (slotb >> 8);
    int within = slotb & 255;
    int gw = (gv << 10) + (within << 2) + (threadIdx.x >> 6);  // local row
    int l = threadIdx.x & 63;
    int es = l >> 4;                 // edge slot 0..3
    int col = (l & 15) * 8;          // 8 dims per lane
    int n = gw & (NN - 1);
    long base = (long)gw * HID;
    const float* hrp = hr + base + col;
    float4 hrA = *(const float4*)(hrp);
    float4 hrB = *(const float4*)(hrp + 4);
    float4 aA = *(const float4*)(avec + col);
    float4 aB = *(const float4*)(avec + col + 4);
    float m = -INFINITY, ssum = 0.f;
    float4 acA = make_float4(0.f, 0.f, 0.f, 0.f);
    float4 acB = make_float4(0.f, 0.f, 0.f, 0.f);
    int beg = ptr[n], end = ptr[n + 1];
    const float* hlv = hl + (long)(gw >> 14) * NN * HID;   // view base in pass

    for (int j = beg + es; j < end; j += 4) {
        int sn = csr_src[j];                 // group-uniform (broadcast)
        const float* hp = hlv + ((sn << 7) + col);
        float4 hA = *(const float4*)(hp);
        float4 hB = *(const float4*)(hp + 4);
        // t = lrelu(h + hr) = max(s,0) + 0.2*min(s,0); p = dot(t, a) over 8 dims
        float p;
        {
            float s0 = hA.x + hrA.x, s1 = hA.y + hrA.y, s2 = hA.z + hrA.z, s3 = hA.w + hrA.w;
            float s4 = hB.x + hrB.x, s5 = hB.y + hrB.y, s6 = hB.z + hrB.z, s7 = hB.w + hrB.w;
            float t0 = fmaxf(s0, 0.f) + NEG_SLOPE * fminf(s0, 0.f);
            float t1 = fmaxf(s1, 0.f) + NEG_SLOPE * fminf(s1, 0.f);
            float t2 = fmaxf(s2, 0.f) + NEG_SLOPE * fminf(s2, 0.f);
            float t3 = fmaxf(s3, 0.f) + NEG_SLOPE * fminf(s3, 0.f);
            float t4 = fmaxf(s4, 0.f) + NEG_SLOPE * fminf(s4, 0.f);
            float t5 = fmaxf(s5, 0.f) + NEG_SLOPE * fminf(s5, 0.f);
            float t6 = fmaxf(s6, 0.f) + NEG_SLOPE * fminf(s6, 0.f);
            float t7 = fmaxf(s7, 0.f) + NEG_SLOPE * fminf(s7, 0.f);
            p = t0 * aA.x + t1 * aA.y + t2 * aA.z + t3 * aA.w
              + t4 * aB.x + t5 * aB.y + t6 * aB.z + t7 * aB.w;
        }
        // reduce over the 4-lane head group (head = (l&15)>>2)
        p += __shfl_xor(p, 1, 4);
        p += __shfl_xor(p, 2, 4);
        // online softmax update for this slot
        float mn = fmaxf(m, p);
        float cold = __expf(m - mn);         // first edge: exp(-inf)=0
        float w = __expf(p - mn);
        ssum = ssum * cold + w;
        acA.x = acA.x * cold + w * hA.x;
        acA.y = acA.y * cold + w * hA.y;
        acA.z = acA.z * cold + w * hA.z;
        acA.w = acA.w * cold + w * hA.w;
        acB.x = acB.x * cold + w * hB.x;
        acB.y = acB.y * cold + w * hB.y;
        acB.z = acB.z * cold + w * hB.z;
        acB.w = acB.w * cold + w * hB.w;
        m = mn;
    }

    // merge the 4 slots (lanes l, l^16, l^32 hold same dims, different slots)
    float mG = fmaxf(m, __shfl_xor(m, 16));
    mG = fmaxf(mG, __shfl_xor(mG, 32));
    float sc = (m > -INFINITY) ? __expf(m - mG) : 0.f;   // empty slot -> 0
    ssum *= sc;
    acA.x *= sc; acA.y *= sc; acA.z *= sc; acA.w *= sc;
    acB.x *= sc; acB.y *= sc; acB.z *= sc; acB.w *= sc;
    ssum += __shfl_xor(ssum, 16); ssum += __shfl_xor(ssum, 32);
    acA.x += __shfl_xor(acA.x, 16); acA.x += __shfl_xor(acA.x, 32);
    acA.y += __shfl_xor(acA.y, 16); acA.y += __shfl_xor(acA.y, 32);
    acA.z += __shfl_xor(acA.z, 16); acA.z += __shfl_xor(acA.z, 32);
    acA.w += __shfl_xor(acA.w, 16); acA.w += __shfl_xor(acA.w, 32);
    acB.x += __shfl_xor(acB.x, 16); acB.x += __shfl_xor(acB.x, 32);
    acB.y += __shfl_xor(acB.y, 16); acB.y += __shfl_xor(acB.y, 32);
    acB.z += __shfl_xor(acB.z, 16); acB.z += __shfl_xor(acB.z, 32);
    acB.w += __shfl_xor(acB.w, 16); acB.w += __shfl_xor(acB.w, 32);

    if (es == 0) {
        float inv = 1.f / (ssum + 1e-16f);   // deg==0 -> acc=0 -> out = res
        const float* rp = res + base + col;
        float4 rA = *(const float4*)(rp);
        float4 rB = *(const float4*)(rp + 4);
        float o[8];
        o[0] = acA.x * inv + rA.x; o[1] = acA.y * inv + rA.y;
        o[2] = acA.z * inv + rA.z; o[3] = acA.w * inv + rA.w;
        o[4] = acB.x * inv + rB.x; o[5] = acB.y * inv + rB.y;
        o[6] = acB.z * inv + rB.z; o[7] = acB.w * inv + rB.w;
        if (act) {
#pragma unroll
            for (int i = 0; i < 8; i++)
                o[i] = o[i] > 0.f ? o[i] : (__expf(o[i]) - 1.f);
        }
        float* op = hout + base + col;
        *(float4*)(op)     = make_float4(o[0], o[1], o[2], o[3]);
        *(float4*)(op + 4) = make_float4(o[4], o[5], o[6], o[7]);
    }
}

// ---------------------------------------------------------------------------
// MFMA GEMM: C[M][128] = A[M][128] @ W[128][128], W pre-split bf16 (hi,lo),
// A split in-register. 3-product split: Ah*Wh + Ah*Wl + Al*Wh (~17-bit
// effective mantissa). LDS-free: A-frag (8 consecutive k of one row) loads
// straight from global as 2x float4; W-frags come pre-laid-out.
// Block = 128 rows x 128 cols, 4 waves in 2x2, each wave 64x64 = 16 acc tiles.
// blockIdx.z selects (mat0,C0) / (mat1,C1).
// ---------------------------------------------------------------------------
__global__ __launch_bounds__(256) void gemm_mfma(const float* __restrict__ A,
                                                 const unsigned short* __restrict__ whi,
                                                 const unsigned short* __restrict__ wlo,
                                                 int mat0, int mat1,
                                                 float* __restrict__ C0, float* __restrict__ C1,
                                                 const float* __restrict__ bias, int doRelu) {
    int mat = (blockIdx.z == 0) ? mat0 : mat1;
    float* C = (blockIdx.z == 0) ? C0 : C1;
    const unsigned short* bh = whi + (long)mat * 16384;
    const unsigned short* bl = wlo + (long)mat * 16384;
    int tid = threadIdx.x;
    int w = tid >> 6, l = tid & 63;
    int rh = w >> 1, ch = w & 1;          // wave's row-half / col-half
    long row0 = (long)blockIdx.x * 128 + rh * 64;
    int lr = l & 15;                      // A-frag row within tile
    int lk = (l >> 4) << 3;               // A-frag k offset
    floatx4 acc[4][4];
#pragma unroll
    for (int i = 0; i < 4; i++)
#pragma unroll
        for (int j = 0; j < 4; j++) acc[i][j] = (floatx4)0.f;

    for (int kt = 0; kt < 4; kt++) {
        shortx8 bhf[4], blf[4];
#pragma unroll
        for (int ctl = 0; ctl < 4; ctl++) {
            int ct = ch * 4 + ctl;
            long fi = ((long)(ct * 4 + kt) * 64 + l) * 8;
            bhf[ctl] = *(const shortx8*)(bh + fi);
            blf[ctl] = *(const shortx8*)(bl + fi);
        }
#pragma unroll
        for (int rt = 0; rt < 4; rt++) {
            const float* ap = A + (row0 + rt * 16 + lr) * HID + kt * 32 + lk;
            float4 x0 = *(const float4*)(ap);
            float4 x1 = *(const float4*)(ap + 4);
            float xs[8] = {x0.x, x0.y, x0.z, x0.w, x1.x, x1.y, x1.z, x1.w};
            shortx8 ah, al;
#pragma unroll
            for (int i = 0; i < 8; i++) {
                unsigned hb = bf_hi_bits(xs[i]);
                float r = xs[i] - __uint_as_float(hb << 16);
                unsigned lb = bf_hi_bits(r);
                ah[i] = (short)hb;
                al[i] = (short)lb;
            }
#pragma unroll
            for (int ctl = 0; ctl < 4; ctl++)
                acc[rt][ctl] = __builtin_amdgcn_mfma_f32_16x16x32_bf16(ah, bhf[ctl], acc[rt][ctl], 0, 0, 0);
#pragma unroll
            for (int ctl = 0; ctl < 4; ctl++)
                acc[rt][ctl] = __builtin_amdgcn_mfma_f32_16x16x32_bf16(ah, blf[ctl], acc[rt][ctl], 0, 0, 0);
#pragma unroll
            for (int ctl = 0; ctl < 4; ctl++)
                acc[rt][ctl] = __builtin_amdgcn_mfma_f32_16x16x32_bf16(al, bhf[ctl], acc[rt][ctl], 0, 0, 0);
        }
    }
    // epilogue: C/D layout col = lane&15, row = (lane>>4)*4 + reg  [m89-verified]
    int lrow4 = (l >> 4) * 4;
#pragma unroll
    for (int rt = 0; rt < 4; rt++) {
#pragma unroll
        for (int ctl = 0; ctl < 4; ctl++) {
            int col = ch * 64 + ctl * 16 + lr;
            float badd = bias ? bias[col] : 0.f;
#pragma unroll
            for (int rg = 0; rg < 4; rg++) {
                long row = row0 + rt * 16 + lrow4 + rg;
                float v = acc[rt][ctl][rg] + badd;
                if (doRelu) v = fmaxf(v, 0.f);
                C[row * HID + col] = v;
            }
        }
    }
}

// ---------------------------------------------------------------------------
// Accumulate 0.25 * sum over the pass's k views into emb  (emb pre-zeroed)
// ---------------------------------------------------------------------------
__global__ void acc_kernel(const float* __restrict__ h, float* __restrict__ emb, int k) {
    int i = blockIdx.x * 256 + threadIdx.x;  // over NN*32 float4s
    const float4* h4 = (const float4*)h;
    float4 s = make_float4(0.f, 0.f, 0.f, 0.f);
    for (int lv = 0; lv < k; lv++) {
        float4 a = h4[i + (long)lv * NN * 32];
        s.x += a.x; s.y += a.y; s.z += a.z; s.w += a.w;
    }
    float4* e4 = (float4*)emb;
    float4 o = e4[i];
    o.x += 0.25f * s.x; o.y += 0.25f * s.y; o.z += 0.25f * s.z; o.w += 0.25f * s.w;
    e4[i] = o;
}

// ---------------------------------------------------------------------------
// Final logits: out[n] = z[n][:] . Wh2 + bh2   (one wave per node)
// ---------------------------------------------------------------------------
__global__ void logits_kernel(const float* __restrict__ z, const float* __restrict__ Wh2,
                              const float* __restrict__ bh2, float* __restrict__ out) {
    int w = (blockIdx.x * 256 + threadIdx.x) >> 6;
    int l = threadIdx.x & 63;
    float v = z[(long)w * HID + l] * Wh2[l] + z[(long)w * HID + 64 + l] * Wh2[64 + l];
    v += __shfl_xor(v, 32);
    v += __shfl_xor(v, 16);
    v += __shfl_xor(v, 8);
    v += __shfl_xor(v, 4);
    v += __shfl_xor(v, 2);
    v += __shfl_xor(v, 1);
    if (l == 0) out[w] = v + bh2[0];
}

// ---------------------------------------------------------------------------
extern "C" void kernel_launch(void* const* d_in, const int* in_sizes, int n_in,
                              void* d_out, int out_size, void* d_ws, size_t ws_size,
                              hipStream_t stream) {
    const float* x    = (const float*)d_in[0];
    const int*   ei   = (const int*)d_in[1];      // [2][E]: src then dst
    const float* W0l  = (const float*)d_in[3];
    const float* W0r  = (const float*)d_in[4];
    const float* a0   = (const float*)d_in[5];
    const float* Wres0= (const float*)d_in[6];
    const float* Wl   = (const float*)d_in[7];    // [2][128][128]
    const float* Wr   = (const float*)d_in[8];
    const float* att  = (const float*)d_in[9];    // [2][4][32]
    const float* Wh1  = (const float*)d_in[10];
    const float* bh1  = (const float*)d_in[11];
    const float* Wh2  = (const float*)d_in[12];
    const float* bh2  = (const float*)d_in[13];
    float* out = (float*)d_out;

    const int* src = ei;
    const int* dst = ei + EE;

    // workspace: emb | ptr | ptrw | csr | whi | wlo | (256B-aligned) bufA | bufB | bufC
    char* wsb = (char*)d_ws;
    float* emb = (float*)wsb;                               // [NN][128]
    size_t off = (size_t)NN * HID * 4;
    int* ptr  = (int*)(wsb + off);  off += (NN + 1) * 4;    // [NN+1]
    int* ptrw = (int*)(wsb + off);  off += NN * 4;          // [NN]
    int* csr  = (int*)(wsb + off);  off += (size_t)EE * 4;  // [EE]
    off = (off + 255) & ~(size_t)255;
    unsigned short* whi = (unsigned short*)(wsb + off); off += 5 * 16384 * 2;  // 160 KB
    unsigned short* wlo = (unsigned short*)(wsb + off); off += 5 * 16384 * 2;  // 160 KB
    off = (off + 255) & ~(size_t)255;
    size_t fixedBytes = off;

    // ws-adaptive pass sizing: k views per pass, k in {4,2,1}
    int k = 4;
    while (k > 1 && fixedBytes + 3ull * k * NN * HID * 4 > ws_size) k >>= 1;
    long K = (long)k * NN;           // rows per pass
    int npass = 4 / k;
    int gvPerXcd = (int)(K / 1024) / 8;   // graph-view chunks per XCD

    float* bufA = (float*)(wsb + off);            // [K][128]
    float* bufB = bufA + K * HID;                 // [K][128]
    float* bufC = bufB + K * HID;                 // [K][128]

    // --- CSR build (shared by all views/layers) + weight split ---
    hipMemsetAsync(ptrw, 0, NN * sizeof(int), stream);
    count_kernel<<<EE / 256, 256, 0, stream>>>(dst, ptrw);
    scan_kernel<<<1, 1024, 0, stream>>>(ptrw, ptr);
    scatter_kernel<<<EE / 256, 256, 0, stream>>>(src, dst, ptrw, csr);
    wsplit_kernel<<<dim3(8, 5), 256, 0, stream>>>(Wl, Wr, Wh1, whi, wlo);

    // --- emb = 0 ---
    hipMemsetAsync(emb, 0, (size_t)NN * HID * sizeof(float), stream);

    for (int p = 0; p < npass; p++) {
        int viewBase = p * k;
        // layer 0: hl->A, hr->B, hres->C;  attn0 (res=C) -> B (h0)
        l0_kernel<<<dim3(L0_BLOCKS, 3), 256, 0, stream>>>(x, W0l, W0r, Wres0,
                                                          bufA, bufB, bufC, viewBase, K);
        attn_kernel<<<K / 4, 256, 0, stream>>>(bufA, bufB, bufC, ptr, csr, a0, bufB, 1, gvPerXcd);
        // layer 1: gemm B->(A=hl via Wl0, C=hr via Wr0);  attn1 (res=B) -> C (h1)
        gemm_mfma<<<dim3(K / 128, 1, 2), 256, 0, stream>>>(bufB, whi, wlo, 0, 1,
                                                           bufA, bufC, nullptr, 0);
        attn_kernel<<<K / 4, 256, 0, stream>>>(bufA, bufC, bufB, ptr, csr, att, bufC, 1, gvPerXcd);
        // layer 2: gemm C->(A=hl via Wl1, B=hr via Wr1);  attn2 (res=C, no act) -> B (h2)
        gemm_mfma<<<dim3(K / 128, 1, 2), 256, 0, stream>>>(bufC, whi, wlo, 2, 3,
                                                           bufA, bufB, nullptr, 0);
        attn_kernel<<<K / 4, 256, 0, stream>>>(bufA, bufB, bufC, ptr, csr, att + HID, bufB, 0, gvPerXcd);
        // accumulate mean over views
        acc_kernel<<<NN * 32 / 256, 256, 0, stream>>>(bufB, emb, k);
    }

    // --- head: z = relu(emb@Wh1+bh1) -> bufA;  logits(bufA) -> out ---
    gemm_mfma<<<dim3(NN / 128, 1, 1), 256, 0, stream>>>(emb, whi, wlo, 4, 4,
                                                        bufA, bufA, bh1, 1);
    logits_kernel<<<NN * 64 / 256, 256, 0, stream>>>(bufA, Wh2, bh2, out);
}

// Round 10
// 392.574 us; speedup vs baseline: 1.0047x; 1.0047x over previous
//
#include <hip/hip_runtime.h>
#include <hip/hip_bf16.h>
#include <math.h>

#define NN 16384       // nodes
#define EE 131072      // edges
#define FIN 16
#define HID 128
#define NEG_SLOPE 0.2f

typedef float  floatx4 __attribute__((ext_vector_type(4)));
typedef short  shortx8 __attribute__((ext_vector_type(8)));

// fp32 -> bf16 RNE split helpers (hi catches top 8 mantissa bits, lo the next 8)
__device__ inline unsigned bf_hi_bits(float x) {
    unsigned u = __float_as_uint(x);
    return (u + 0x7FFFu + ((u >> 16) & 1u)) >> 16;
}

// ---------------------------------------------------------------------------
// CSR build
// ---------------------------------------------------------------------------
__global__ void count_kernel(const int* __restrict__ dst, int* __restrict__ deg) {
    int e = blockIdx.x * 256 + threadIdx.x;
    atomicAdd(&deg[dst[e]], 1);
}

__global__ __launch_bounds__(1024) void scan_kernel(int* __restrict__ degw /* in: deg, out: offsets */,
                                                    int* __restrict__ ptr) {
    __shared__ int sums[1024];
    int t = threadIdx.x;
    int base = t * 16;
    int local[16];
    int s = 0;
#pragma unroll
    for (int i = 0; i < 16; i++) { local[i] = degw[base + i]; s += local[i]; }
    sums[t] = s;
    __syncthreads();
    for (int off = 1; off < 1024; off <<= 1) {
        int v = (t >= off) ? sums[t - off] : 0;
        __syncthreads();
        sums[t] += v;
        __syncthreads();
    }
    int ex = (t == 0) ? 0 : sums[t - 1];
#pragma unroll
    for (int i = 0; i < 16; i++) {
        ptr[base + i] = ex;
        degw[base + i] = ex;   // working copy for scatter
        ex += local[i];
    }
    if (t == 1023) ptr[NN] = sums[1023];
}

__global__ void scatter_kernel(const int* __restrict__ src, const int* __restrict__ dst,
                               int* __restrict__ ptrw, int* __restrict__ csr_src) {
    int e = blockIdx.x * 256 + threadIdx.x;
    int p = atomicAdd(&ptrw[dst[e]], 1);
    csr_src[p] = src[e];
}

// ---------------------------------------------------------------------------
// Weight pre-split into MFMA B-fragment layout, once per call.
// mat: 0=Wl[0], 1=Wr[0], 2=Wl[1], 3=Wr[1], 4=Wh1. For mfma_f32_16x16x32_bf16,
// B-frag: lane l supplies B[k=(l>>4)*8+j][col=l&15] for j=0..7. Stored so one
// lane's 8 bf16 are contiguous: idx = ((mat*32 + ct*4 + kt)*64 + l)*8 + j.
// ---------------------------------------------------------------------------
__global__ void wsplit_kernel(const float* __restrict__ Wl, const float* __restrict__ Wr,
                              const float* __restrict__ Wh1,
                              unsigned short* __restrict__ hi, unsigned short* __restrict__ lo) {
    int mat = blockIdx.y;
    const float* W = (mat == 0) ? Wl : (mat == 1) ? Wr : (mat == 2) ? Wl + HID * HID
                   : (mat == 3) ? Wr + HID * HID : Wh1;
    int ct = blockIdx.x;             // col tile 0..7
    int t = threadIdx.x;
    int kt = t >> 6, l = t & 63;
    long obase = (((long)mat * 32 + (ct * 4 + kt)) * 64 + l) * 8;
    int c = ct * 16 + (l & 15);
    int kbase = kt * 32 + ((l >> 4) << 3);
#pragma unroll
    for (int j = 0; j < 8; j++) {
        float x = W[(kbase + j) * HID + c];
        unsigned hb = bf_hi_bits(x);
        float r = x - __uint_as_float(hb << 16);
        unsigned lb = bf_hi_bits(r);
        hi[obase + j] = (unsigned short)hb;
        lo[obase + j] = (unsigned short)lb;
    }
}

// ---------------------------------------------------------------------------
// Layer 0 linear. History: r5 LDS-staging version 80us (L2-bound); r8 fused
// 2-col/thread version 47us (176 VGPR, 8% occ, latency-starved); r9 split-y
// version 84us (3x blocks -> 2.2x WRITE amplification from too many live
// write streams). r10: r8's clean single-grid structure (2048 blocks, one
// block-iter writes all 3 streams) but 1 col/thread -> 48 weight VGPRs.
// Waves {0,1} cover 128 cols of even rows, waves {2,3} odd rows.
// Stores 4 B/lane, 256 B contiguous per wave per stream = full lines.
// ---------------------------------------------------------------------------
#define L0_BLOCKS 2048
__global__ __launch_bounds__(256, 4) void l0_kernel(const float* __restrict__ x,
                                                    const float* __restrict__ W0l,
                                                    const float* __restrict__ W0r,
                                                    const float* __restrict__ Wres,
                                                    float* __restrict__ hl,
                                                    float* __restrict__ hr,
                                                    float* __restrict__ hres,
                                                    int viewBase, long totalRows) {
    int tid = threadIdx.x;
    int l = tid & 63;
    int w = tid >> 6;                      // wave 0..3
    int col = ((w & 1) << 6) + l;          // this thread's column 0..127
    int rsel = w >> 1;                     // row parity within iter
    float wl[FIN], wr[FIN], ws[FIN];
#pragma unroll
    for (int k = 0; k < FIN; k++) {
        wl[k] = W0l[k * HID + col];
        wr[k] = W0r[k * HID + col];
        ws[k] = Wres[k * HID + col];
    }
    for (long lw = (long)blockIdx.x * 2 + rsel; lw < totalRows;
         lw += (long)L0_BLOCKS * 2) {
        int v = viewBase + (int)(lw >> 14);            // absolute view
        int n = (int)(lw & (NN - 1));                  // node
        const float* xr = x + (long)n * FIN;
        float a0 = 0.f, a1 = 0.f, a2 = 0.f;
#pragma unroll
        for (int k = 0; k < FIN; k++) {
            float xk = xr[k];                          // wave-uniform (s_load)
            if (k == 0 && (v & 1)) xk = -xk;           // flip x for views 1,3
            if (k == 1 && (v & 2)) xk = -xk;           // flip y for views 2,3
            a0 += xk * wl[k];
            a1 += xk * wr[k];
            a2 += xk * ws[k];
        }
        long base = lw * HID + col;
        hl[base]   = a0;
        hr[base]   = a1;
        hres[base] = a2;
    }
}

// ---------------------------------------------------------------------------
// GATv2 edge attention + aggregate + residual + (optional) ELU.
// Wave = 4 edge-slots x 16 lanes, 8 dims/lane; head-dot reduce = 2 shuffles
// over a 4-lane group; slots run independent online softmax over an
// interleaved quarter of the edge list; one cross-slot merge per node.
// XCD swizzle: graph-view chunk pinned to one XCD (L2-resident working set).
// hout may alias hr or res (row-local reads before the only write).
// ---------------------------------------------------------------------------
__global__ __launch_bounds__(256) void attn_kernel(const float* __restrict__ hl,
                                                   const float* __restrict__ hr,
                                                   const float* __restrict__ res,
                                                   const int* __restrict__ ptr,
                                                   const int* __restrict__ csr_src,
                                                   const float* __restrict__ avec,
                                                   float* __restrict__ hout,
                                                   int act,
                                                   int gvPerXcd) {
    int xcd = blockIdx.x & 7;
    int slotb = blockIdx.x >> 3;
    int gv = xcd * gvPerXcd + (slotb >> 8);
    int within = slotb & 255;
    int gw = (gv << 10) + (within << 2) + (threadIdx.x >> 6);  // local row
    int l = threadIdx.x & 63;
    int es = l >> 4;                 // edge slot 0..3
    int col = (l & 15) * 8;          // 8 dims per lane
    int n = gw & (NN - 1);
    long base = (long)gw * HID;
    const float* hrp = hr + base + col;
    float4 hrA = *(const float4*)(hrp);
    float4 hrB = *(const float4*)(hrp + 4);
    float4 aA = *(const float4*)(avec + col);
    float4 aB = *(const float4*)(avec + col + 4);
    float m = -INFINITY, ssum = 0.f;
    float4 acA = make_float4(0.f, 0.f, 0.f, 0.f);
    float4 acB = make_float4(0.f, 0.f, 0.f, 0.f);
    int beg = ptr[n], end = ptr[n + 1];
    const float* hlv = hl + (long)(gw >> 14) * NN * HID;   // view base in pass

    for (int j = beg + es; j < end; j += 4) {
        int sn = csr_src[j];                 // group-uniform (broadcast)
        const float* hp = hlv + ((sn << 7) + col);
        float4 hA = *(const float4*)(hp);
        float4 hB = *(const float4*)(hp + 4);
        // t = lrelu(h + hr) = max(s,0) + 0.2*min(s,0); p = dot(t, a) over 8 dims
        float p;
        {
            float s0 = hA.x + hrA.x, s1 = hA.y + hrA.y, s2 = hA.z + hrA.z, s3 = hA.w + hrA.w;
            float s4 = hB.x + hrB.x, s5 = hB.y + hrB.y, s6 = hB.z + hrB.z, s7 = hB.w + hrB.w;
            float t0 = fmaxf(s0, 0.f) + NEG_SLOPE * fminf(s0, 0.f);
            float t1 = fmaxf(s1, 0.f) + NEG_SLOPE * fminf(s1, 0.f);
            float t2 = fmaxf(s2, 0.f) + NEG_SLOPE * fminf(s2, 0.f);
            float t3 = fmaxf(s3, 0.f) + NEG_SLOPE * fminf(s3, 0.f);
            float t4 = fmaxf(s4, 0.f) + NEG_SLOPE * fminf(s4, 0.f);
            float t5 = fmaxf(s5, 0.f) + NEG_SLOPE * fminf(s5, 0.f);
            float t6 = fmaxf(s6, 0.f) + NEG_SLOPE * fminf(s6, 0.f);
            float t7 = fmaxf(s7, 0.f) + NEG_SLOPE * fminf(s7, 0.f);
            p = t0 * aA.x + t1 * aA.y + t2 * aA.z + t3 * aA.w
              + t4 * aB.x + t5 * aB.y + t6 * aB.z + t7 * aB.w;
        }
        // reduce over the 4-lane head group (head = (l&15)>>2)
        p += __shfl_xor(p, 1, 4);
        p += __shfl_xor(p, 2, 4);
        // online softmax update for this slot
        float mn = fmaxf(m, p);
        float cold = __expf(m - mn);         // first edge: exp(-inf)=0
        float w = __expf(p - mn);
        ssum = ssum * cold + w;
        acA.x = acA.x * cold + w * hA.x;
        acA.y = acA.y * cold + w * hA.y;
        acA.z = acA.z * cold + w * hA.z;
        acA.w = acA.w * cold + w * hA.w;
        acB.x = acB.x * cold + w * hB.x;
        acB.y = acB.y * cold + w * hB.y;
        acB.z = acB.z * cold + w * hB.z;
        acB.w = acB.w * cold + w * hB.w;
        m = mn;
    }

    // merge the 4 slots (lanes l, l^16, l^32 hold same dims, different slots)
    float mG = fmaxf(m, __shfl_xor(m, 16));
    mG = fmaxf(mG, __shfl_xor(mG, 32));
    float sc = (m > -INFINITY) ? __expf(m - mG) : 0.f;   // empty slot -> 0
    ssum *= sc;
    acA.x *= sc; acA.y *= sc; acA.z *= sc; acA.w *= sc;
    acB.x *= sc; acB.y *= sc; acB.z *= sc; acB.w *= sc;
    ssum += __shfl_xor(ssum, 16); ssum += __shfl_xor(ssum, 32);
    acA.x += __shfl_xor(acA.x, 16); acA.x += __shfl_xor(acA.x, 32);
    acA.y += __shfl_xor(acA.y, 16); acA.y += __shfl_xor(acA.y, 32);
    acA.z += __shfl_xor(acA.z, 16); acA.z += __shfl_xor(acA.z, 32);
    acA.w += __shfl_xor(acA.w, 16); acA.w += __shfl_xor(acA.w, 32);
    acB.x += __shfl_xor(acB.x, 16); acB.x += __shfl_xor(acB.x, 32);
    acB.y += __shfl_xor(acB.y, 16); acB.y += __shfl_xor(acB.y, 32);
    acB.z += __shfl_xor(acB.z, 16); acB.z += __shfl_xor(acB.z, 32);
    acB.w += __shfl_xor(acB.w, 16); acB.w += __shfl_xor(acB.w, 32);

    if (es == 0) {
        float inv = 1.f / (ssum + 1e-16f);   // deg==0 -> acc=0 -> out = res
        const float* rp = res + base + col;
        float4 rA = *(const float4*)(rp);
        float4 rB = *(const float4*)(rp + 4);
        float o[8];
        o[0] = acA.x * inv + rA.x; o[1] = acA.y * inv + rA.y;
        o[2] = acA.z * inv + rA.z; o[3] = acA.w * inv + rA.w;
        o[4] = acB.x * inv + rB.x; o[5] = acB.y * inv + rB.y;
        o[6] = acB.z * inv + rB.z; o[7] = acB.w * inv + rB.w;
        if (act) {
#pragma unroll
            for (int i = 0; i < 8; i++)
                o[i] = o[i] > 0.f ? o[i] : (__expf(o[i]) - 1.f);
        }
        float* op = hout + base + col;
        *(float4*)(op)     = make_float4(o[0], o[1], o[2], o[3]);
        *(float4*)(op + 4) = make_float4(o[4], o[5], o[6], o[7]);
    }
}

// ---------------------------------------------------------------------------
// MFMA GEMM: C[M][128] = A[M][128] @ W[128][128], W pre-split bf16 (hi,lo),
// A split in-register. 3-product split: Ah*Wh + Ah*Wl + Al*Wh (~17-bit
// effective mantissa). LDS-free: A-frag (8 consecutive k of one row) loads
// straight from global as 2x float4; W-frags come pre-laid-out.
// Block = 128 rows x 128 cols, 4 waves in 2x2, each wave 64x64 = 16 acc tiles.
// blockIdx.z selects (mat0,C0) / (mat1,C1).
// ---------------------------------------------------------------------------
__global__ __launch_bounds__(256) void gemm_mfma(const float* __restrict__ A,
                                                 const unsigned short* __restrict__ whi,
                                                 const unsigned short* __restrict__ wlo,
                                                 int mat0, int mat1,
                                                 float* __restrict__ C0, float* __restrict__ C1,
                                                 const float* __restrict__ bias, int doRelu) {
    int mat = (blockIdx.z == 0) ? mat0 : mat1;
    float* C = (blockIdx.z == 0) ? C0 : C1;
    const unsigned short* bh = whi + (long)mat * 16384;
    const unsigned short* bl = wlo + (long)mat * 16384;
    int tid = threadIdx.x;
    int w = tid >> 6, l = tid & 63;
    int rh = w >> 1, ch = w & 1;          // wave's row-half / col-half
    long row0 = (long)blockIdx.x * 128 + rh * 64;
    int lr = l & 15;                      // A-frag row within tile
    int lk = (l >> 4) << 3;               // A-frag k offset
    floatx4 acc[4][4];
#pragma unroll
    for (int i = 0; i < 4; i++)
#pragma unroll
        for (int j = 0; j < 4; j++) acc[i][j] = (floatx4)0.f;

    for (int kt = 0; kt < 4; kt++) {
        shortx8 bhf[4], blf[4];
#pragma unroll
        for (int ctl = 0; ctl < 4; ctl++) {
            int ct = ch * 4 + ctl;
            long fi = ((long)(ct * 4 + kt) * 64 + l) * 8;
            bhf[ctl] = *(const shortx8*)(bh + fi);
            blf[ctl] = *(const shortx8*)(bl + fi);
        }
#pragma unroll
        for (int rt = 0; rt < 4; rt++) {
            const float* ap = A + (row0 + rt * 16 + lr) * HID + kt * 32 + lk;
            float4 x0 = *(const float4*)(ap);
            float4 x1 = *(const float4*)(ap + 4);
            float xs[8] = {x0.x, x0.y, x0.z, x0.w, x1.x, x1.y, x1.z, x1.w};
            shortx8 ah, al;
#pragma unroll
            for (int i = 0; i < 8; i++) {
                unsigned hb = bf_hi_bits(xs[i]);
                float r = xs[i] - __uint_as_float(hb << 16);
                unsigned lb = bf_hi_bits(r);
                ah[i] = (short)hb;
                al[i] = (short)lb;
            }
#pragma unroll
            for (int ctl = 0; ctl < 4; ctl++)
                acc[rt][ctl] = __builtin_amdgcn_mfma_f32_16x16x32_bf16(ah, bhf[ctl], acc[rt][ctl], 0, 0, 0);
#pragma unroll
            for (int ctl = 0; ctl < 4; ctl++)
                acc[rt][ctl] = __builtin_amdgcn_mfma_f32_16x16x32_bf16(ah, blf[ctl], acc[rt][ctl], 0, 0, 0);
#pragma unroll
            for (int ctl = 0; ctl < 4; ctl++)
                acc[rt][ctl] = __builtin_amdgcn_mfma_f32_16x16x32_bf16(al, bhf[ctl], acc[rt][ctl], 0, 0, 0);
        }
    }
    // epilogue: C/D layout col = lane&15, row = (lane>>4)*4 + reg  [m89-verified]
    int lrow4 = (l >> 4) * 4;
#pragma unroll
    for (int rt = 0; rt < 4; rt++) {
#pragma unroll
        for (int ctl = 0; ctl < 4; ctl++) {
            int col = ch * 64 + ctl * 16 + lr;
            float badd = bias ? bias[col] : 0.f;
#pragma unroll
            for (int rg = 0; rg < 4; rg++) {
                long row = row0 + rt * 16 + lrow4 + rg;
                float v = acc[rt][ctl][rg] + badd;
                if (doRelu) v = fmaxf(v, 0.f);
                C[row * HID + col] = v;
            }
        }
    }
}

// ---------------------------------------------------------------------------
// Accumulate 0.25 * sum over the pass's k views into emb  (emb pre-zeroed)
// ---------------------------------------------------------------------------
__global__ void acc_kernel(const float* __restrict__ h, float* __restrict__ emb, int k) {
    int i = blockIdx.x * 256 + threadIdx.x;  // over NN*32 float4s
    const float4* h4 = (const float4*)h;
    float4 s = make_float4(0.f, 0.f, 0.f, 0.f);
    for (int lv = 0; lv < k; lv++) {
        float4 a = h4[i + (long)lv * NN * 32];
        s.x += a.x; s.y += a.y; s.z += a.z; s.w += a.w;
    }
    float4* e4 = (float4*)emb;
    float4 o = e4[i];
    o.x += 0.25f * s.x; o.y += 0.25f * s.y; o.z += 0.25f * s.z; o.w += 0.25f * s.w;
    e4[i] = o;
}

// ---------------------------------------------------------------------------
// Final logits: out[n] = z[n][:] . Wh2 + bh2   (one wave per node)
// ---------------------------------------------------------------------------
__global__ void logits_kernel(const float* __restrict__ z, const float* __restrict__ Wh2,
                              const float* __restrict__ bh2, float* __restrict__ out) {
    int w = (blockIdx.x * 256 + threadIdx.x) >> 6;
    int l = threadIdx.x & 63;
    float v = z[(long)w * HID + l] * Wh2[l] + z[(long)w * HID + 64 + l] * Wh2[64 + l];
    v += __shfl_xor(v, 32);
    v += __shfl_xor(v, 16);
    v += __shfl_xor(v, 8);
    v += __shfl_xor(v, 4);
    v += __shfl_xor(v, 2);
    v += __shfl_xor(v, 1);
    if (l == 0) out[w] = v + bh2[0];
}

// ---------------------------------------------------------------------------
extern "C" void kernel_launch(void* const* d_in, const int* in_sizes, int n_in,
                              void* d_out, int out_size, void* d_ws, size_t ws_size,
                              hipStream_t stream) {
    const float* x    = (const float*)d_in[0];
    const int*   ei   = (const int*)d_in[1];      // [2][E]: src then dst
    const float* W0l  = (const float*)d_in[3];
    const float* W0r  = (const float*)d_in[4];
    const float* a0   = (const float*)d_in[5];
    const float* Wres0= (const float*)d_in[6];
    const float* Wl   = (const float*)d_in[7];    // [2][128][128]
    const float* Wr   = (const float*)d_in[8];
    const float* att  = (const float*)d_in[9];    // [2][4][32]
    const float* Wh1  = (const float*)d_in[10];
    const float* bh1  = (const float*)d_in[11];
    const float* Wh2  = (const float*)d_in[12];
    const float* bh2  = (const float*)d_in[13];
    float* out = (float*)d_out;

    const int* src = ei;
    const int* dst = ei + EE;

    // workspace: emb | ptr | ptrw | csr | whi | wlo | (256B-aligned) bufA | bufB | bufC
    char* wsb = (char*)d_ws;
    float* emb = (float*)wsb;                               // [NN][128]
    size_t off = (size_t)NN * HID * 4;
    int* ptr  = (int*)(wsb + off);  off += (NN + 1) * 4;    // [NN+1]
    int* ptrw = (int*)(wsb + off);  off += NN * 4;          // [NN]
    int* csr  = (int*)(wsb + off);  off += (size_t)EE * 4;  // [EE]
    off = (off + 255) & ~(size_t)255;
    unsigned short* whi = (unsigned short*)(wsb + off); off += 5 * 16384 * 2;  // 160 KB
    unsigned short* wlo = (unsigned short*)(wsb + off); off += 5 * 16384 * 2;  // 160 KB
    off = (off + 255) & ~(size_t)255;
    size_t fixedBytes = off;

    // ws-adaptive pass sizing: k views per pass, k in {4,2,1}
    int k = 4;
    while (k > 1 && fixedBytes + 3ull * k * NN * HID * 4 > ws_size) k >>= 1;
    long K = (long)k * NN;           // rows per pass
    int npass = 4 / k;
    int gvPerXcd = (int)(K / 1024) / 8;   // graph-view chunks per XCD

    float* bufA = (float*)(wsb + off);            // [K][128]
    float* bufB = bufA + K * HID;                 // [K][128]
    float* bufC = bufB + K * HID;                 // [K][128]

    // --- CSR build (shared by all views/layers) + weight split ---
    hipMemsetAsync(ptrw, 0, NN * sizeof(int), stream);
    count_kernel<<<EE / 256, 256, 0, stream>>>(dst, ptrw);
    scan_kernel<<<1, 1024, 0, stream>>>(ptrw, ptr);
    scatter_kernel<<<EE / 256, 256, 0, stream>>>(src, dst, ptrw, csr);
    wsplit_kernel<<<dim3(8, 5), 256, 0, stream>>>(Wl, Wr, Wh1, whi, wlo);

    // --- emb = 0 ---
    hipMemsetAsync(emb, 0, (size_t)NN * HID * sizeof(float), stream);

    for (int p = 0; p < npass; p++) {
        int viewBase = p * k;
        // layer 0: hl->A, hr->B, hres->C;  attn0 (res=C) -> B (h0)
        l0_kernel<<<L0_BLOCKS, 256, 0, stream>>>(x, W0l, W0r, Wres0,
                                                 bufA, bufB, bufC, viewBase, K);
        attn_kernel<<<K / 4, 256, 0, stream>>>(bufA, bufB, bufC, ptr, csr, a0, bufB, 1, gvPerXcd);
        // layer 1: gemm B->(A=hl via Wl0, C=hr via Wr0);  attn1 (res=B) -> C (h1)
        gemm_mfma<<<dim3(K / 128, 1, 2), 256, 0, stream>>>(bufB, whi, wlo, 0, 1,
                                                           bufA, bufC, nullptr, 0);
        attn_kernel<<<K / 4, 256, 0, stream>>>(bufA, bufC, bufB, ptr, csr, att, bufC, 1, gvPerXcd);
        // layer 2: gemm C->(A=hl via Wl1, B=hr via Wr1);  attn2 (res=C, no act) -> B (h2)
        gemm_mfma<<<dim3(K / 128, 1, 2), 256, 0, stream>>>(bufC, whi, wlo, 2, 3,
                                                           bufA, bufB, nullptr, 0);
        attn_kernel<<<K / 4, 256, 0, stream>>>(bufA, bufB, bufC, ptr, csr, att + HID, bufB, 0, gvPerXcd);
        // accumulate mean over views
        acc_kernel<<<NN * 32 / 256, 256, 0, stream>>>(bufB, emb, k);
    }

    // --- head: z = relu(emb@Wh1+bh1) -> bufA;  logits(bufA) -> out ---
    gemm_mfma<<<dim3(NN / 128, 1, 1), 256, 0, stream>>>(emb, whi, wlo, 4, 4,
                                                        bufA, bufA, bh1, 1);
    logits_kernel<<<NN * 64 / 256, 256, 0, stream>>>(bufA, Wh2, bh2, out);
}

// Round 11
// 376.951 us; speedup vs baseline: 1.0464x; 1.0414x over previous
//
#include <hip/hip_runtime.h>
#include <hip/hip_bf16.h>
#include <math.h>

#define NN 16384       // nodes
#define EE 131072      // edges
#define FIN 16
#define HID 128
#define NEG_SLOPE 0.2f

typedef float  floatx4 __attribute__((ext_vector_type(4)));
typedef short  shortx8 __attribute__((ext_vector_type(8)));

// fp32 -> bf16 RNE split helpers (hi catches top 8 mantissa bits, lo the next 8)
__device__ inline unsigned bf_hi_bits(float x) {
    unsigned u = __float_as_uint(x);
    return (u + 0x7FFFu + ((u >> 16) & 1u)) >> 16;
}

// ---------------------------------------------------------------------------
// CSR build
// ---------------------------------------------------------------------------
__global__ void count_kernel(const int* __restrict__ dst, int* __restrict__ deg) {
    int e = blockIdx.x * 256 + threadIdx.x;
    atomicAdd(&deg[dst[e]], 1);
}

__global__ __launch_bounds__(1024) void scan_kernel(int* __restrict__ degw /* in: deg, out: offsets */,
                                                    int* __restrict__ ptr) {
    __shared__ int sums[1024];
    int t = threadIdx.x;
    int base = t * 16;
    int local[16];
    int s = 0;
#pragma unroll
    for (int i = 0; i < 16; i++) { local[i] = degw[base + i]; s += local[i]; }
    sums[t] = s;
    __syncthreads();
    for (int off = 1; off < 1024; off <<= 1) {
        int v = (t >= off) ? sums[t - off] : 0;
        __syncthreads();
        sums[t] += v;
        __syncthreads();
    }
    int ex = (t == 0) ? 0 : sums[t - 1];
#pragma unroll
    for (int i = 0; i < 16; i++) {
        ptr[base + i] = ex;
        degw[base + i] = ex;   // working copy for scatter
        ex += local[i];
    }
    if (t == 1023) ptr[NN] = sums[1023];
}

__global__ void scatter_kernel(const int* __restrict__ src, const int* __restrict__ dst,
                               int* __restrict__ ptrw, int* __restrict__ csr_src) {
    int e = blockIdx.x * 256 + threadIdx.x;
    int p = atomicAdd(&ptrw[dst[e]], 1);
    csr_src[p] = src[e];
}

// ---------------------------------------------------------------------------
// Weight pre-split into MFMA B-fragment layout, once per call.
// mat: 0=Wl[0], 1=Wr[0], 2=Wl[1], 3=Wr[1], 4=Wh1. For mfma_f32_16x16x32_bf16,
// B-frag: lane l supplies B[k=(l>>4)*8+j][col=l&15] for j=0..7. Stored so one
// lane's 8 bf16 are contiguous: idx = ((mat*32 + ct*4 + kt)*64 + l)*8 + j.
// ---------------------------------------------------------------------------
__global__ void wsplit_kernel(const float* __restrict__ Wl, const float* __restrict__ Wr,
                              const float* __restrict__ Wh1,
                              unsigned short* __restrict__ hi, unsigned short* __restrict__ lo) {
    int mat = blockIdx.y;
    const float* W = (mat == 0) ? Wl : (mat == 1) ? Wr : (mat == 2) ? Wl + HID * HID
                   : (mat == 3) ? Wr + HID * HID : Wh1;
    int ct = blockIdx.x;             // col tile 0..7
    int t = threadIdx.x;
    int kt = t >> 6, l = t & 63;
    long obase = (((long)mat * 32 + (ct * 4 + kt)) * 64 + l) * 8;
    int c = ct * 16 + (l & 15);
    int kbase = kt * 32 + ((l >> 4) << 3);
#pragma unroll
    for (int j = 0; j < 8; j++) {
        float x = W[(kbase + j) * HID + c];
        unsigned hb = bf_hi_bits(x);
        float r = x - __uint_as_float(hb << 16);
        unsigned lb = bf_hi_bits(r);
        hi[obase + j] = (unsigned short)hb;
        lo[obase + j] = (unsigned short)lb;
    }
}

// ---------------------------------------------------------------------------
// Layer 0 linear. Empirical rule from r5/r8 (exact 96MB writes) vs r9/r10
// (1.5-2.2x WRITE amplification + phantom 32MB FETCH): waves must write FULL
// 512B rows per stream. r8 did that but held all 3 matrices per thread
// (176 VGPR -> 8% occupancy -> 47us). Now: 192-thread blocks, wave w owns
// stream w (hl/hr/hres); lane holds 2 cols of ONE matrix = 32 weight VGPRs;
// each wave stores one full 512B row of its stream per iteration. The three
// waves share the wave-uniform x row (SGPR loads).
// ---------------------------------------------------------------------------
#define L0_BLOCKS 4096
__global__ __launch_bounds__(192, 6) void l0_kernel(const float* __restrict__ x,
                                                    const float* __restrict__ W0l,
                                                    const float* __restrict__ W0r,
                                                    const float* __restrict__ Wres,
                                                    float* __restrict__ hl,
                                                    float* __restrict__ hr,
                                                    float* __restrict__ hres,
                                                    int viewBase, long totalRows) {
    int tid = threadIdx.x;
    int l = tid & 63;
    int w = tid >> 6;                      // wave 0..2 -> stream
    const float* W = (w == 0) ? W0l : (w == 1) ? W0r : Wres;
    float* outp    = (w == 0) ? hl  : (w == 1) ? hr  : hres;
    int c2 = l * 2;
    float2 w2[FIN];
#pragma unroll
    for (int k = 0; k < FIN; k++) w2[k] = *(const float2*)(W + k * HID + c2);

    for (long lw = blockIdx.x; lw < totalRows; lw += L0_BLOCKS) {
        int v = viewBase + (int)(lw >> 14);            // absolute view
        int n = (int)(lw & (NN - 1));                  // node
        const float* xr = x + (long)n * FIN;
        float a0 = 0.f, a1 = 0.f;
#pragma unroll
        for (int k = 0; k < FIN; k++) {
            float xk = xr[k];                          // wave-uniform (s_load)
            if (k == 0 && (v & 1)) xk = -xk;           // flip x for views 1,3
            if (k == 1 && (v & 2)) xk = -xk;           // flip y for views 2,3
            a0 += xk * w2[k].x;
            a1 += xk * w2[k].y;
        }
        *(float2*)(outp + lw * HID + c2) = make_float2(a0, a1);
    }
}

// ---------------------------------------------------------------------------
// GATv2 edge attention + aggregate + residual + (optional) ELU.
// Wave = 4 edge-slots x 16 lanes, 8 dims/lane; head-dot reduce = 2 shuffles
// over a 4-lane group; slots run independent online softmax over an
// interleaved quarter of the edge list; one cross-slot merge per node.
// XCD swizzle: graph-view chunk pinned to one XCD (L2-resident working set).
// hout may alias hr or res (row-local reads before the only write).
// ---------------------------------------------------------------------------
__global__ __launch_bounds__(256) void attn_kernel(const float* __restrict__ hl,
                                                   const float* __restrict__ hr,
                                                   const float* __restrict__ res,
                                                   const int* __restrict__ ptr,
                                                   const int* __restrict__ csr_src,
                                                   const float* __restrict__ avec,
                                                   float* __restrict__ hout,
                                                   int act,
                                                   int gvPerXcd) {
    int xcd = blockIdx.x & 7;
    int slotb = blockIdx.x >> 3;
    int gv = xcd * gvPerXcd + (slotb >> 8);
    int within = slotb & 255;
    int gw = (gv << 10) + (within << 2) + (threadIdx.x >> 6);  // local row
    int l = threadIdx.x & 63;
    int es = l >> 4;                 // edge slot 0..3
    int col = (l & 15) * 8;          // 8 dims per lane
    int n = gw & (NN - 1);
    long base = (long)gw * HID;
    const float* hrp = hr + base + col;
    float4 hrA = *(const float4*)(hrp);
    float4 hrB = *(const float4*)(hrp + 4);
    float4 aA = *(const float4*)(avec + col);
    float4 aB = *(const float4*)(avec + col + 4);
    float m = -INFINITY, ssum = 0.f;
    float4 acA = make_float4(0.f, 0.f, 0.f, 0.f);
    float4 acB = make_float4(0.f, 0.f, 0.f, 0.f);
    int beg = ptr[n], end = ptr[n + 1];
    const float* hlv = hl + (long)(gw >> 14) * NN * HID;   // view base in pass

    for (int j = beg + es; j < end; j += 4) {
        int sn = csr_src[j];                 // group-uniform (broadcast)
        const float* hp = hlv + ((sn << 7) + col);
        float4 hA = *(const float4*)(hp);
        float4 hB = *(const float4*)(hp + 4);
        // t = lrelu(h + hr) = max(s,0) + 0.2*min(s,0); p = dot(t, a) over 8 dims
        float p;
        {
            float s0 = hA.x + hrA.x, s1 = hA.y + hrA.y, s2 = hA.z + hrA.z, s3 = hA.w + hrA.w;
            float s4 = hB.x + hrB.x, s5 = hB.y + hrB.y, s6 = hB.z + hrB.z, s7 = hB.w + hrB.w;
            float t0 = fmaxf(s0, 0.f) + NEG_SLOPE * fminf(s0, 0.f);
            float t1 = fmaxf(s1, 0.f) + NEG_SLOPE * fminf(s1, 0.f);
            float t2 = fmaxf(s2, 0.f) + NEG_SLOPE * fminf(s2, 0.f);
            float t3 = fmaxf(s3, 0.f) + NEG_SLOPE * fminf(s3, 0.f);
            float t4 = fmaxf(s4, 0.f) + NEG_SLOPE * fminf(s4, 0.f);
            float t5 = fmaxf(s5, 0.f) + NEG_SLOPE * fminf(s5, 0.f);
            float t6 = fmaxf(s6, 0.f) + NEG_SLOPE * fminf(s6, 0.f);
            float t7 = fmaxf(s7, 0.f) + NEG_SLOPE * fminf(s7, 0.f);
            p = t0 * aA.x + t1 * aA.y + t2 * aA.z + t3 * aA.w
              + t4 * aB.x + t5 * aB.y + t6 * aB.z + t7 * aB.w;
        }
        // reduce over the 4-lane head group (head = (l&15)>>2)
        p += __shfl_xor(p, 1, 4);
        p += __shfl_xor(p, 2, 4);
        // online softmax update for this slot
        float mn = fmaxf(m, p);
        float cold = __expf(m - mn);         // first edge: exp(-inf)=0
        float w = __expf(p - mn);
        ssum = ssum * cold + w;
        acA.x = acA.x * cold + w * hA.x;
        acA.y = acA.y * cold + w * hA.y;
        acA.z = acA.z * cold + w * hA.z;
        acA.w = acA.w * cold + w * hA.w;
        acB.x = acB.x * cold + w * hB.x;
        acB.y = acB.y * cold + w * hB.y;
        acB.z = acB.z * cold + w * hB.z;
        acB.w = acB.w * cold + w * hB.w;
        m = mn;
    }

    // merge the 4 slots (lanes l, l^16, l^32 hold same dims, different slots)
    float mG = fmaxf(m, __shfl_xor(m, 16));
    mG = fmaxf(mG, __shfl_xor(mG, 32));
    float sc = (m > -INFINITY) ? __expf(m - mG) : 0.f;   // empty slot -> 0
    ssum *= sc;
    acA.x *= sc; acA.y *= sc; acA.z *= sc; acA.w *= sc;
    acB.x *= sc; acB.y *= sc; acB.z *= sc; acB.w *= sc;
    ssum += __shfl_xor(ssum, 16); ssum += __shfl_xor(ssum, 32);
    acA.x += __shfl_xor(acA.x, 16); acA.x += __shfl_xor(acA.x, 32);
    acA.y += __shfl_xor(acA.y, 16); acA.y += __shfl_xor(acA.y, 32);
    acA.z += __shfl_xor(acA.z, 16); acA.z += __shfl_xor(acA.z, 32);
    acA.w += __shfl_xor(acA.w, 16); acA.w += __shfl_xor(acA.w, 32);
    acB.x += __shfl_xor(acB.x, 16); acB.x += __shfl_xor(acB.x, 32);
    acB.y += __shfl_xor(acB.y, 16); acB.y += __shfl_xor(acB.y, 32);
    acB.z += __shfl_xor(acB.z, 16); acB.z += __shfl_xor(acB.z, 32);
    acB.w += __shfl_xor(acB.w, 16); acB.w += __shfl_xor(acB.w, 32);

    if (es == 0) {
        float inv = 1.f / (ssum + 1e-16f);   // deg==0 -> acc=0 -> out = res
        const float* rp = res + base + col;
        float4 rA = *(const float4*)(rp);
        float4 rB = *(const float4*)(rp + 4);
        float o[8];
        o[0] = acA.x * inv + rA.x; o[1] = acA.y * inv + rA.y;
        o[2] = acA.z * inv + rA.z; o[3] = acA.w * inv + rA.w;
        o[4] = acB.x * inv + rB.x; o[5] = acB.y * inv + rB.y;
        o[6] = acB.z * inv + rB.z; o[7] = acB.w * inv + rB.w;
        if (act) {
#pragma unroll
            for (int i = 0; i < 8; i++)
                o[i] = o[i] > 0.f ? o[i] : (__expf(o[i]) - 1.f);
        }
        float* op = hout + base + col;
        *(float4*)(op)     = make_float4(o[0], o[1], o[2], o[3]);
        *(float4*)(op + 4) = make_float4(o[4], o[5], o[6], o[7]);
    }
}

// ---------------------------------------------------------------------------
// MFMA GEMM: C[M][128] = A[M][128] @ W[128][128], W pre-split bf16 (hi,lo),
// A split in-register. 3-product split: Ah*Wh + Ah*Wl + Al*Wh (~17-bit
// effective mantissa). LDS-free: A-frag (8 consecutive k of one row) loads
// straight from global as 2x float4; W-frags come pre-laid-out.
// Block = 128 rows x 128 cols, 4 waves in 2x2, each wave 64x64 = 16 acc tiles.
// blockIdx.z selects (mat0,C0) / (mat1,C1).
// ---------------------------------------------------------------------------
__global__ __launch_bounds__(256) void gemm_mfma(const float* __restrict__ A,
                                                 const unsigned short* __restrict__ whi,
                                                 const unsigned short* __restrict__ wlo,
                                                 int mat0, int mat1,
                                                 float* __restrict__ C0, float* __restrict__ C1,
                                                 const float* __restrict__ bias, int doRelu) {
    int mat = (blockIdx.z == 0) ? mat0 : mat1;
    float* C = (blockIdx.z == 0) ? C0 : C1;
    const unsigned short* bh = whi + (long)mat * 16384;
    const unsigned short* bl = wlo + (long)mat * 16384;
    int tid = threadIdx.x;
    int w = tid >> 6, l = tid & 63;
    int rh = w >> 1, ch = w & 1;          // wave's row-half / col-half
    long row0 = (long)blockIdx.x * 128 + rh * 64;
    int lr = l & 15;                      // A-frag row within tile
    int lk = (l >> 4) << 3;               // A-frag k offset
    floatx4 acc[4][4];
#pragma unroll
    for (int i = 0; i < 4; i++)
#pragma unroll
        for (int j = 0; j < 4; j++) acc[i][j] = (floatx4)0.f;

    for (int kt = 0; kt < 4; kt++) {
        shortx8 bhf[4], blf[4];
#pragma unroll
        for (int ctl = 0; ctl < 4; ctl++) {
            int ct = ch * 4 + ctl;
            long fi = ((long)(ct * 4 + kt) * 64 + l) * 8;
            bhf[ctl] = *(const shortx8*)(bh + fi);
            blf[ctl] = *(const shortx8*)(bl + fi);
        }
#pragma unroll
        for (int rt = 0; rt < 4; rt++) {
            const float* ap = A + (row0 + rt * 16 + lr) * HID + kt * 32 + lk;
            float4 x0 = *(const float4*)(ap);
            float4 x1 = *(const float4*)(ap + 4);
            float xs[8] = {x0.x, x0.y, x0.z, x0.w, x1.x, x1.y, x1.z, x1.w};
            shortx8 ah, al;
#pragma unroll
            for (int i = 0; i < 8; i++) {
                unsigned hb = bf_hi_bits(xs[i]);
                float r = xs[i] - __uint_as_float(hb << 16);
                unsigned lb = bf_hi_bits(r);
                ah[i] = (short)hb;
                al[i] = (short)lb;
            }
#pragma unroll
            for (int ctl = 0; ctl < 4; ctl++)
                acc[rt][ctl] = __builtin_amdgcn_mfma_f32_16x16x32_bf16(ah, bhf[ctl], acc[rt][ctl], 0, 0, 0);
#pragma unroll
            for (int ctl = 0; ctl < 4; ctl++)
                acc[rt][ctl] = __builtin_amdgcn_mfma_f32_16x16x32_bf16(ah, blf[ctl], acc[rt][ctl], 0, 0, 0);
#pragma unroll
            for (int ctl = 0; ctl < 4; ctl++)
                acc[rt][ctl] = __builtin_amdgcn_mfma_f32_16x16x32_bf16(al, bhf[ctl], acc[rt][ctl], 0, 0, 0);
        }
    }
    // epilogue: C/D layout col = lane&15, row = (lane>>4)*4 + reg  [m89-verified]
    int lrow4 = (l >> 4) * 4;
#pragma unroll
    for (int rt = 0; rt < 4; rt++) {
#pragma unroll
        for (int ctl = 0; ctl < 4; ctl++) {
            int col = ch * 64 + ctl * 16 + lr;
            float badd = bias ? bias[col] : 0.f;
#pragma unroll
            for (int rg = 0; rg < 4; rg++) {
                long row = row0 + rt * 16 + lrow4 + rg;
                float v = acc[rt][ctl][rg] + badd;
                if (doRelu) v = fmaxf(v, 0.f);
                C[row * HID + col] = v;
            }
        }
    }
}

// ---------------------------------------------------------------------------
// Accumulate 0.25 * sum over the pass's k views into emb  (emb pre-zeroed)
// ---------------------------------------------------------------------------
__global__ void acc_kernel(const float* __restrict__ h, float* __restrict__ emb, int k) {
    int i = blockIdx.x * 256 + threadIdx.x;  // over NN*32 float4s
    const float4* h4 = (const float4*)h;
    float4 s = make_float4(0.f, 0.f, 0.f, 0.f);
    for (int lv = 0; lv < k; lv++) {
        float4 a = h4[i + (long)lv * NN * 32];
        s.x += a.x; s.y += a.y; s.z += a.z; s.w += a.w;
    }
    float4* e4 = (float4*)emb;
    float4 o = e4[i];
    o.x += 0.25f * s.x; o.y += 0.25f * s.y; o.z += 0.25f * s.z; o.w += 0.25f * s.w;
    e4[i] = o;
}

// ---------------------------------------------------------------------------
// Final logits: out[n] = z[n][:] . Wh2 + bh2   (one wave per node)
// ---------------------------------------------------------------------------
__global__ void logits_kernel(const float* __restrict__ z, const float* __restrict__ Wh2,
                              const float* __restrict__ bh2, float* __restrict__ out) {
    int w = (blockIdx.x * 256 + threadIdx.x) >> 6;
    int l = threadIdx.x & 63;
    float v = z[(long)w * HID + l] * Wh2[l] + z[(long)w * HID + 64 + l] * Wh2[64 + l];
    v += __shfl_xor(v, 32);
    v += __shfl_xor(v, 16);
    v += __shfl_xor(v, 8);
    v += __shfl_xor(v, 4);
    v += __shfl_xor(v, 2);
    v += __shfl_xor(v, 1);
    if (l == 0) out[w] = v + bh2[0];
}

// ---------------------------------------------------------------------------
extern "C" void kernel_launch(void* const* d_in, const int* in_sizes, int n_in,
                              void* d_out, int out_size, void* d_ws, size_t ws_size,
                              hipStream_t stream) {
    const float* x    = (const float*)d_in[0];
    const int*   ei   = (const int*)d_in[1];      // [2][E]: src then dst
    const float* W0l  = (const float*)d_in[3];
    const float* W0r  = (const float*)d_in[4];
    const float* a0   = (const float*)d_in[5];
    const float* Wres0= (const float*)d_in[6];
    const float* Wl   = (const float*)d_in[7];    // [2][128][128]
    const float* Wr   = (const float*)d_in[8];
    const float* att  = (const float*)d_in[9];    // [2][4][32]
    const float* Wh1  = (const float*)d_in[10];
    const float* bh1  = (const float*)d_in[11];
    const float* Wh2  = (const float*)d_in[12];
    const float* bh2  = (const float*)d_in[13];
    float* out = (float*)d_out;

    const int* src = ei;
    const int* dst = ei + EE;

    // workspace: emb | ptr | ptrw | csr | whi | wlo | (256B-aligned) bufA | bufB | bufC
    char* wsb = (char*)d_ws;
    float* emb = (float*)wsb;                               // [NN][128]
    size_t off = (size_t)NN * HID * 4;
    int* ptr  = (int*)(wsb + off);  off += (NN + 1) * 4;    // [NN+1]
    int* ptrw = (int*)(wsb + off);  off += NN * 4;          // [NN]
    int* csr  = (int*)(wsb + off);  off += (size_t)EE * 4;  // [EE]
    off = (off + 255) & ~(size_t)255;
    unsigned short* whi = (unsigned short*)(wsb + off); off += 5 * 16384 * 2;  // 160 KB
    unsigned short* wlo = (unsigned short*)(wsb + off); off += 5 * 16384 * 2;  // 160 KB
    off = (off + 255) & ~(size_t)255;
    size_t fixedBytes = off;

    // ws-adaptive pass sizing: k views per pass, k in {4,2,1}
    int k = 4;
    while (k > 1 && fixedBytes + 3ull * k * NN * HID * 4 > ws_size) k >>= 1;
    long K = (long)k * NN;           // rows per pass
    int npass = 4 / k;
    int gvPerXcd = (int)(K / 1024) / 8;   // graph-view chunks per XCD

    float* bufA = (float*)(wsb + off);            // [K][128]
    float* bufB = bufA + K * HID;                 // [K][128]
    float* bufC = bufB + K * HID;                 // [K][128]

    // --- CSR build (shared by all views/layers) + weight split ---
    hipMemsetAsync(ptrw, 0, NN * sizeof(int), stream);
    count_kernel<<<EE / 256, 256, 0, stream>>>(dst, ptrw);
    scan_kernel<<<1, 1024, 0, stream>>>(ptrw, ptr);
    scatter_kernel<<<EE / 256, 256, 0, stream>>>(src, dst, ptrw, csr);
    wsplit_kernel<<<dim3(8, 5), 256, 0, stream>>>(Wl, Wr, Wh1, whi, wlo);

    // --- emb = 0 ---
    hipMemsetAsync(emb, 0, (size_t)NN * HID * sizeof(float), stream);

    for (int p = 0; p < npass; p++) {
        int viewBase = p * k;
        // layer 0: hl->A, hr->B, hres->C;  attn0 (res=C) -> B (h0)
        l0_kernel<<<L0_BLOCKS, 192, 0, stream>>>(x, W0l, W0r, Wres0,
                                                 bufA, bufB, bufC, viewBase, K);
        attn_kernel<<<K / 4, 256, 0, stream>>>(bufA, bufB, bufC, ptr, csr, a0, bufB, 1, gvPerXcd);
        // layer 1: gemm B->(A=hl via Wl0, C=hr via Wr0);  attn1 (res=B) -> C (h1)
        gemm_mfma<<<dim3(K / 128, 1, 2), 256, 0, stream>>>(bufB, whi, wlo, 0, 1,
                                                           bufA, bufC, nullptr, 0);
        attn_kernel<<<K / 4, 256, 0, stream>>>(bufA, bufC, bufB, ptr, csr, att, bufC, 1, gvPerXcd);
        // layer 2: gemm C->(A=hl via Wl1, B=hr via Wr1);  attn2 (res=C, no act) -> B (h2)
        gemm_mfma<<<dim3(K / 128, 1, 2), 256, 0, stream>>>(bufC, whi, wlo, 2, 3,
                                                           bufA, bufB, nullptr, 0);
        attn_kernel<<<K / 4, 256, 0, stream>>>(bufA, bufB, bufC, ptr, csr, att + HID, bufB, 0, gvPerXcd);
        // accumulate mean over views
        acc_kernel<<<NN * 32 / 256, 256, 0, stream>>>(bufB, emb, k);
    }

    // --- head: z = relu(emb@Wh1+bh1) -> bufA;  logits(bufA) -> out ---
    gemm_mfma<<<dim3(NN / 128, 1, 1), 256, 0, stream>>>(emb, whi, wlo, 4, 4,
                                                        bufA, bufA, bh1, 1);
    logits_kernel<<<NN * 64 / 256, 256, 0, stream>>>(bufA, Wh2, bh2, out);
}

// Round 12
// 376.444 us; speedup vs baseline: 1.0478x; 1.0013x over previous
//
#include <hip/hip_runtime.h>
#include <hip/hip_bf16.h>
#include <math.h>

#define NN 16384       // nodes
#define EE 131072      // edges
#define FIN 16
#define HID 128
#define NEG_SLOPE 0.2f

typedef float  floatx4 __attribute__((ext_vector_type(4)));
typedef short  shortx8 __attribute__((ext_vector_type(8)));

// fp32 -> bf16 RNE split helpers (hi catches top 8 mantissa bits, lo the next 8)
__device__ inline unsigned bf_hi_bits(float x) {
    unsigned u = __float_as_uint(x);
    return (u + 0x7FFFu + ((u >> 16) & 1u)) >> 16;
}

// ---------------------------------------------------------------------------
// CSR build
// ---------------------------------------------------------------------------
__global__ void count_kernel(const int* __restrict__ dst, int* __restrict__ deg) {
    int e = blockIdx.x * 256 + threadIdx.x;
    atomicAdd(&deg[dst[e]], 1);
}

__global__ __launch_bounds__(1024) void scan_kernel(int* __restrict__ degw /* in: deg, out: offsets */,
                                                    int* __restrict__ ptr) {
    __shared__ int sums[1024];
    int t = threadIdx.x;
    int base = t * 16;
    int local[16];
    int s = 0;
#pragma unroll
    for (int i = 0; i < 16; i++) { local[i] = degw[base + i]; s += local[i]; }
    sums[t] = s;
    __syncthreads();
    for (int off = 1; off < 1024; off <<= 1) {
        int v = (t >= off) ? sums[t - off] : 0;
        __syncthreads();
        sums[t] += v;
        __syncthreads();
    }
    int ex = (t == 0) ? 0 : sums[t - 1];
#pragma unroll
    for (int i = 0; i < 16; i++) {
        ptr[base + i] = ex;
        degw[base + i] = ex;   // working copy for scatter
        ex += local[i];
    }
    if (t == 1023) ptr[NN] = sums[1023];
}

__global__ void scatter_kernel(const int* __restrict__ src, const int* __restrict__ dst,
                               int* __restrict__ ptrw, int* __restrict__ csr_src) {
    int e = blockIdx.x * 256 + threadIdx.x;
    int p = atomicAdd(&ptrw[dst[e]], 1);
    csr_src[p] = src[e];
}

// ---------------------------------------------------------------------------
// Weight pre-split into MFMA B-fragment layout, once per call.
// mat: 0=Wl[0], 1=Wr[0], 2=Wl[1], 3=Wr[1], 4=Wh1. For mfma_f32_16x16x32_bf16,
// B-frag: lane l supplies B[k=(l>>4)*8+j][col=l&15] for j=0..7. Stored so one
// lane's 8 bf16 are contiguous: idx = ((mat*32 + ct*4 + kt)*64 + l)*8 + j.
// ---------------------------------------------------------------------------
__global__ void wsplit_kernel(const float* __restrict__ Wl, const float* __restrict__ Wr,
                              const float* __restrict__ Wh1,
                              unsigned short* __restrict__ hi, unsigned short* __restrict__ lo) {
    int mat = blockIdx.y;
    const float* W = (mat == 0) ? Wl : (mat == 1) ? Wr : (mat == 2) ? Wl + HID * HID
                   : (mat == 3) ? Wr + HID * HID : Wh1;
    int ct = blockIdx.x;             // col tile 0..7
    int t = threadIdx.x;
    int kt = t >> 6, l = t & 63;
    long obase = (((long)mat * 32 + (ct * 4 + kt)) * 64 + l) * 8;
    int c = ct * 16 + (l & 15);
    int kbase = kt * 32 + ((l >> 4) << 3);
#pragma unroll
    for (int j = 0; j < 8; j++) {
        float x = W[(kbase + j) * HID + c];
        unsigned hb = bf_hi_bits(x);
        float r = x - __uint_as_float(hb << 16);
        unsigned lb = bf_hi_bits(r);
        hi[obase + j] = (unsigned short)hb;
        lo[obase + j] = (unsigned short)lb;
    }
}

// ---------------------------------------------------------------------------
// Layer 0 linear, LDS-staged memcpy-shaped stores. History: every variant
// whose concurrent dirty-write window was large (r9/r10/r11 grid-stride, high
// occupancy) showed 1.5-2.2x WRITE amplification + phantom FETCH; short-lived
// sequential blocks (r5) were exact. This version: 512 short-lived blocks,
// each owns 128 CONSECUTIVE rows; per stream, compute the 64KB tile into LDS
// (weights in 16 VGPRs, x reads wave-uniform), then dump it sequentially as
// 16 float4/thread (4KB contiguous per instruction) - a literal memcpy shape.
// ---------------------------------------------------------------------------
#define L0T 128
__global__ __launch_bounds__(256) void l0_kernel(const float* __restrict__ x,
                                                 const float* __restrict__ W0l,
                                                 const float* __restrict__ W0r,
                                                 const float* __restrict__ Wres,
                                                 float* __restrict__ hl,
                                                 float* __restrict__ hr,
                                                 float* __restrict__ hres,
                                                 int viewBase) {
    __shared__ float tile[L0T * HID];          // 64 KB
    int t = threadIdx.x;
    int c = t & 127;
    int h = t >> 7;                            // row parity 0/1
    long row0 = (long)blockIdx.x * L0T;
    int v = viewBase + (int)(row0 >> 14);      // view constant per block (16384%128==0)
    int flip0 = (v & 1) ? -1 : 1;
    int flip1 = (v & 2) ? -1 : 1;

#pragma unroll
    for (int ph = 0; ph < 3; ph++) {
        const float* W = (ph == 0) ? W0l : (ph == 1) ? W0r : Wres;
        float* outp    = (ph == 0) ? hl  : (ph == 1) ? hr  : hres;
        float wreg[FIN];
#pragma unroll
        for (int k = 0; k < FIN; k++) wreg[k] = W[k * HID + c];
        if (ph) __syncthreads();               // tile consumed by previous store phase
        for (int i = 0; i < L0T / 2; i++) {
            int r = h + 2 * i;
            int n = (int)((row0 + r) & (NN - 1));
            const float* xr = x + (long)n * FIN;
            float a = (flip0 * xr[0]) * wreg[0] + (flip1 * xr[1]) * wreg[1];
#pragma unroll
            for (int k = 2; k < FIN; k++) a += xr[k] * wreg[k];
            tile[r * HID + c] = a;
        }
        __syncthreads();
        // sequential dump: 4096 float4s, 16 per thread, 4KB contiguous/instr
        const float4* tl4 = (const float4*)tile;
        float4* o4 = (float4*)(outp + row0 * HID);
#pragma unroll
        for (int q = 0; q < 16; q++) {
            int g = t + q * 256;
            o4[g] = tl4[g];
        }
    }
}

// ---------------------------------------------------------------------------
// GATv2 edge attention + aggregate + residual + (optional) ELU.
// Wave = 4 edge-slots x 16 lanes, 8 dims/lane; head-dot reduce = 2 shuffles
// over a 4-lane group. r12: 2-edge pairwise unroll per slot (edges j, j+4)
// halves the serial online-softmax chain; typical deg=8 -> one pair per
// slot, no tail. One cross-slot merge per node at the end.
// XCD swizzle: graph-view chunk pinned to one XCD (L2-resident working set).
// hout may alias hr or res (row-local reads before the only write).
// ---------------------------------------------------------------------------
__global__ __launch_bounds__(256) void attn_kernel(const float* __restrict__ hl,
                                                   const float* __restrict__ hr,
                                                   const float* __restrict__ res,
                                                   const int* __restrict__ ptr,
                                                   const int* __restrict__ csr_src,
                                                   const float* __restrict__ avec,
                                                   float* __restrict__ hout,
                                                   int act,
                                                   int gvPerXcd) {
    int xcd = blockIdx.x & 7;
    int slotb = blockIdx.x >> 3;
    int gv = xcd * gvPerXcd + (slotb >> 8);
    int within = slotb & 255;
    int gw = (gv << 10) + (within << 2) + (threadIdx.x >> 6);  // local row
    int l = threadIdx.x & 63;
    int es = l >> 4;                 // edge slot 0..3
    int col = (l & 15) * 8;          // 8 dims per lane
    int n = gw & (NN - 1);
    long base = (long)gw * HID;
    const float* hrp = hr + base + col;
    float4 hrA = *(const float4*)(hrp);
    float4 hrB = *(const float4*)(hrp + 4);
    float4 aA = *(const float4*)(avec + col);
    float4 aB = *(const float4*)(avec + col + 4);
    float m = -INFINITY, ssum = 0.f;
    float4 acA = make_float4(0.f, 0.f, 0.f, 0.f);
    float4 acB = make_float4(0.f, 0.f, 0.f, 0.f);
    int beg = ptr[n], end = ptr[n + 1];
    const float* hlv = hl + (long)(gw >> 14) * NN * HID;   // view base in pass

    int j = beg + es;
    for (; j + 4 < end; j += 8) {
        int sa = csr_src[j];
        int sb = csr_src[j + 4];
        const float* hpa = hlv + ((sa << 7) + col);
        const float* hpb = hlv + ((sb << 7) + col);
        float4 haA = *(const float4*)(hpa);
        float4 haB = *(const float4*)(hpa + 4);
        float4 hbA = *(const float4*)(hpb);
        float4 hbB = *(const float4*)(hpb + 4);
        float pa, pb;
        {
            float s0 = haA.x + hrA.x, s1 = haA.y + hrA.y, s2 = haA.z + hrA.z, s3 = haA.w + hrA.w;
            float s4 = haB.x + hrB.x, s5 = haB.y + hrB.y, s6 = haB.z + hrB.z, s7 = haB.w + hrB.w;
            pa = (fmaxf(s0,0.f) + NEG_SLOPE*fminf(s0,0.f)) * aA.x
               + (fmaxf(s1,0.f) + NEG_SLOPE*fminf(s1,0.f)) * aA.y
               + (fmaxf(s2,0.f) + NEG_SLOPE*fminf(s2,0.f)) * aA.z
               + (fmaxf(s3,0.f) + NEG_SLOPE*fminf(s3,0.f)) * aA.w
               + (fmaxf(s4,0.f) + NEG_SLOPE*fminf(s4,0.f)) * aB.x
               + (fmaxf(s5,0.f) + NEG_SLOPE*fminf(s5,0.f)) * aB.y
               + (fmaxf(s6,0.f) + NEG_SLOPE*fminf(s6,0.f)) * aB.z
               + (fmaxf(s7,0.f) + NEG_SLOPE*fminf(s7,0.f)) * aB.w;
        }
        {
            float s0 = hbA.x + hrA.x, s1 = hbA.y + hrA.y, s2 = hbA.z + hrA.z, s3 = hbA.w + hrA.w;
            float s4 = hbB.x + hrB.x, s5 = hbB.y + hrB.y, s6 = hbB.z + hrB.z, s7 = hbB.w + hrB.w;
            pb = (fmaxf(s0,0.f) + NEG_SLOPE*fminf(s0,0.f)) * aA.x
               + (fmaxf(s1,0.f) + NEG_SLOPE*fminf(s1,0.f)) * aA.y
               + (fmaxf(s2,0.f) + NEG_SLOPE*fminf(s2,0.f)) * aA.z
               + (fmaxf(s3,0.f) + NEG_SLOPE*fminf(s3,0.f)) * aA.w
               + (fmaxf(s4,0.f) + NEG_SLOPE*fminf(s4,0.f)) * aB.x
               + (fmaxf(s5,0.f) + NEG_SLOPE*fminf(s5,0.f)) * aB.y
               + (fmaxf(s6,0.f) + NEG_SLOPE*fminf(s6,0.f)) * aB.z
               + (fmaxf(s7,0.f) + NEG_SLOPE*fminf(s7,0.f)) * aB.w;
        }
        pa += __shfl_xor(pa, 1, 4);
        pb += __shfl_xor(pb, 1, 4);
        pa += __shfl_xor(pa, 2, 4);
        pb += __shfl_xor(pb, 2, 4);
        // pairwise merge, then one chained update covering 2 edges
        float m12 = fmaxf(pa, pb);
        float w1 = __expf(pa - m12);
        float w2 = __expf(pb - m12);
        float mn = fmaxf(m, m12);
        float cold = __expf(m - mn);         // first pair: exp(-inf)=0
        float c12 = __expf(m12 - mn);
        float w1c = w1 * c12, w2c = w2 * c12;
        ssum = ssum * cold + w1c + w2c;
        acA.x = acA.x * cold + w1c * haA.x + w2c * hbA.x;
        acA.y = acA.y * cold + w1c * haA.y + w2c * hbA.y;
        acA.z = acA.z * cold + w1c * haA.z + w2c * hbA.z;
        acA.w = acA.w * cold + w1c * haA.w + w2c * hbA.w;
        acB.x = acB.x * cold + w1c * haB.x + w2c * hbB.x;
        acB.y = acB.y * cold + w1c * haB.y + w2c * hbB.y;
        acB.z = acB.z * cold + w1c * haB.z + w2c * hbB.z;
        acB.w = acB.w * cold + w1c * haB.w + w2c * hbB.w;
        m = mn;
    }
    if (j < end) {
        int sn = csr_src[j];
        const float* hp = hlv + ((sn << 7) + col);
        float4 hA = *(const float4*)(hp);
        float4 hB = *(const float4*)(hp + 4);
        float p;
        {
            float s0 = hA.x + hrA.x, s1 = hA.y + hrA.y, s2 = hA.z + hrA.z, s3 = hA.w + hrA.w;
            float s4 = hB.x + hrB.x, s5 = hB.y + hrB.y, s6 = hB.z + hrB.z, s7 = hB.w + hrB.w;
            p = (fmaxf(s0,0.f) + NEG_SLOPE*fminf(s0,0.f)) * aA.x
              + (fmaxf(s1,0.f) + NEG_SLOPE*fminf(s1,0.f)) * aA.y
              + (fmaxf(s2,0.f) + NEG_SLOPE*fminf(s2,0.f)) * aA.z
              + (fmaxf(s3,0.f) + NEG_SLOPE*fminf(s3,0.f)) * aA.w
              + (fmaxf(s4,0.f) + NEG_SLOPE*fminf(s4,0.f)) * aB.x
              + (fmaxf(s5,0.f) + NEG_SLOPE*fminf(s5,0.f)) * aB.y
              + (fmaxf(s6,0.f) + NEG_SLOPE*fminf(s6,0.f)) * aB.z
              + (fmaxf(s7,0.f) + NEG_SLOPE*fminf(s7,0.f)) * aB.w;
        }
        p += __shfl_xor(p, 1, 4);
        p += __shfl_xor(p, 2, 4);
        float mn = fmaxf(m, p);
        float cold = __expf(m - mn);
        float w = __expf(p - mn);
        ssum = ssum * cold + w;
        acA.x = acA.x * cold + w * hA.x;
        acA.y = acA.y * cold + w * hA.y;
        acA.z = acA.z * cold + w * hA.z;
        acA.w = acA.w * cold + w * hA.w;
        acB.x = acB.x * cold + w * hB.x;
        acB.y = acB.y * cold + w * hB.y;
        acB.z = acB.z * cold + w * hB.z;
        acB.w = acB.w * cold + w * hB.w;
        m = mn;
    }

    // merge the 4 slots (lanes l, l^16, l^32 hold same dims, different slots)
    float mG = fmaxf(m, __shfl_xor(m, 16));
    mG = fmaxf(mG, __shfl_xor(mG, 32));
    float sc = (m > -INFINITY) ? __expf(m - mG) : 0.f;   // empty slot -> 0
    ssum *= sc;
    acA.x *= sc; acA.y *= sc; acA.z *= sc; acA.w *= sc;
    acB.x *= sc; acB.y *= sc; acB.z *= sc; acB.w *= sc;
    ssum += __shfl_xor(ssum, 16); ssum += __shfl_xor(ssum, 32);
    acA.x += __shfl_xor(acA.x, 16); acA.x += __shfl_xor(acA.x, 32);
    acA.y += __shfl_xor(acA.y, 16); acA.y += __shfl_xor(acA.y, 32);
    acA.z += __shfl_xor(acA.z, 16); acA.z += __shfl_xor(acA.z, 32);
    acA.w += __shfl_xor(acA.w, 16); acA.w += __shfl_xor(acA.w, 32);
    acB.x += __shfl_xor(acB.x, 16); acB.x += __shfl_xor(acB.x, 32);
    acB.y += __shfl_xor(acB.y, 16); acB.y += __shfl_xor(acB.y, 32);
    acB.z += __shfl_xor(acB.z, 16); acB.z += __shfl_xor(acB.z, 32);
    acB.w += __shfl_xor(acB.w, 16); acB.w += __shfl_xor(acB.w, 32);

    if (es == 0) {
        float inv = 1.f / (ssum + 1e-16f);   // deg==0 -> acc=0 -> out = res
        const float* rp = res + base + col;
        float4 rA = *(const float4*)(rp);
        float4 rB = *(const float4*)(rp + 4);
        float o[8];
        o[0] = acA.x * inv + rA.x; o[1] = acA.y * inv + rA.y;
        o[2] = acA.z * inv + rA.z; o[3] = acA.w * inv + rA.w;
        o[4] = acB.x * inv + rB.x; o[5] = acB.y * inv + rB.y;
        o[6] = acB.z * inv + rB.z; o[7] = acB.w * inv + rB.w;
        if (act) {
#pragma unroll
            for (int i = 0; i < 8; i++)
                o[i] = o[i] > 0.f ? o[i] : (__expf(o[i]) - 1.f);
        }
        float* op = hout + base + col;
        *(float4*)(op)     = make_float4(o[0], o[1], o[2], o[3]);
        *(float4*)(op + 4) = make_float4(o[4], o[5], o[6], o[7]);
    }
}

// ---------------------------------------------------------------------------
// MFMA GEMM: C[M][128] = A[M][128] @ W[128][128], W pre-split bf16 (hi,lo),
// A split in-register. 3-product split: Ah*Wh + Ah*Wl + Al*Wh (~17-bit
// effective mantissa). LDS-free: A-frag (8 consecutive k of one row) loads
// straight from global as 2x float4; W-frags come pre-laid-out.
// Block = 128 rows x 128 cols, 4 waves in 2x2, each wave 64x64 = 16 acc tiles.
// blockIdx.z selects (mat0,C0) / (mat1,C1).
// ---------------------------------------------------------------------------
__global__ __launch_bounds__(256) void gemm_mfma(const float* __restrict__ A,
                                                 const unsigned short* __restrict__ whi,
                                                 const unsigned short* __restrict__ wlo,
                                                 int mat0, int mat1,
                                                 float* __restrict__ C0, float* __restrict__ C1,
                                                 const float* __restrict__ bias, int doRelu) {
    int mat = (blockIdx.z == 0) ? mat0 : mat1;
    float* C = (blockIdx.z == 0) ? C0 : C1;
    const unsigned short* bh = whi + (long)mat * 16384;
    const unsigned short* bl = wlo + (long)mat * 16384;
    int tid = threadIdx.x;
    int w = tid >> 6, l = tid & 63;
    int rh = w >> 1, ch = w & 1;          // wave's row-half / col-half
    long row0 = (long)blockIdx.x * 128 + rh * 64;
    int lr = l & 15;                      // A-frag row within tile
    int lk = (l >> 4) << 3;               // A-frag k offset
    floatx4 acc[4][4];
#pragma unroll
    for (int i = 0; i < 4; i++)
#pragma unroll
        for (int j = 0; j < 4; j++) acc[i][j] = (floatx4)0.f;

    for (int kt = 0; kt < 4; kt++) {
        shortx8 bhf[4], blf[4];
#pragma unroll
        for (int ctl = 0; ctl < 4; ctl++) {
            int ct = ch * 4 + ctl;
            long fi = ((long)(ct * 4 + kt) * 64 + l) * 8;
            bhf[ctl] = *(const shortx8*)(bh + fi);
            blf[ctl] = *(const shortx8*)(bl + fi);
        }
#pragma unroll
        for (int rt = 0; rt < 4; rt++) {
            const float* ap = A + (row0 + rt * 16 + lr) * HID + kt * 32 + lk;
            float4 x0 = *(const float4*)(ap);
            float4 x1 = *(const float4*)(ap + 4);
            float xs[8] = {x0.x, x0.y, x0.z, x0.w, x1.x, x1.y, x1.z, x1.w};
            shortx8 ah, al;
#pragma unroll
            for (int i = 0; i < 8; i++) {
                unsigned hb = bf_hi_bits(xs[i]);
                float r = xs[i] - __uint_as_float(hb << 16);
                unsigned lb = bf_hi_bits(r);
                ah[i] = (short)hb;
                al[i] = (short)lb;
            }
#pragma unroll
            for (int ctl = 0; ctl < 4; ctl++)
                acc[rt][ctl] = __builtin_amdgcn_mfma_f32_16x16x32_bf16(ah, bhf[ctl], acc[rt][ctl], 0, 0, 0);
#pragma unroll
            for (int ctl = 0; ctl < 4; ctl++)
                acc[rt][ctl] = __builtin_amdgcn_mfma_f32_16x16x32_bf16(ah, blf[ctl], acc[rt][ctl], 0, 0, 0);
#pragma unroll
            for (int ctl = 0; ctl < 4; ctl++)
                acc[rt][ctl] = __builtin_amdgcn_mfma_f32_16x16x32_bf16(al, bhf[ctl], acc[rt][ctl], 0, 0, 0);
        }
    }
    // epilogue: C/D layout col = lane&15, row = (lane>>4)*4 + reg  [m89-verified]
    int lrow4 = (l >> 4) * 4;
#pragma unroll
    for (int rt = 0; rt < 4; rt++) {
#pragma unroll
        for (int ctl = 0; ctl < 4; ctl++) {
            int col = ch * 64 + ctl * 16 + lr;
            float badd = bias ? bias[col] : 0.f;
#pragma unroll
            for (int rg = 0; rg < 4; rg++) {
                long row = row0 + rt * 16 + lrow4 + rg;
                float v = acc[rt][ctl][rg] + badd;
                if (doRelu) v = fmaxf(v, 0.f);
                C[row * HID + col] = v;
            }
        }
    }
}

// ---------------------------------------------------------------------------
// Accumulate 0.25 * sum over the pass's k views into emb  (emb pre-zeroed)
// ---------------------------------------------------------------------------
__global__ void acc_kernel(const float* __restrict__ h, float* __restrict__ emb, int k) {
    int i = blockIdx.x * 256 + threadIdx.x;  // over NN*32 float4s
    const float4* h4 = (const float4*)h;
    float4 s = make_float4(0.f, 0.f, 0.f, 0.f);
    for (int lv = 0; lv < k; lv++) {
        float4 a = h4[i + (long)lv * NN * 32];
        s.x += a.x; s.y += a.y; s.z += a.z; s.w += a.w;
    }
    float4* e4 = (float4*)emb;
    float4 o = e4[i];
    o.x += 0.25f * s.x; o.y += 0.25f * s.y; o.z += 0.25f * s.z; o.w += 0.25f * s.w;
    e4[i] = o;
}

// ---------------------------------------------------------------------------
// Final logits: out[n] = z[n][:] . Wh2 + bh2   (one wave per node)
// ---------------------------------------------------------------------------
__global__ void logits_kernel(const float* __restrict__ z, const float* __restrict__ Wh2,
                              const float* __restrict__ bh2, float* __restrict__ out) {
    int w = (blockIdx.x * 256 + threadIdx.x) >> 6;
    int l = threadIdx.x & 63;
    float v = z[(long)w * HID + l] * Wh2[l] + z[(long)w * HID + 64 + l] * Wh2[64 + l];
    v += __shfl_xor(v, 32);
    v += __shfl_xor(v, 16);
    v += __shfl_xor(v, 8);
    v += __shfl_xor(v, 4);
    v += __shfl_xor(v, 2);
    v += __shfl_xor(v, 1);
    if (l == 0) out[w] = v + bh2[0];
}

// ---------------------------------------------------------------------------
extern "C" void kernel_launch(void* const* d_in, const int* in_sizes, int n_in,
                              void* d_out, int out_size, void* d_ws, size_t ws_size,
                              hipStream_t stream) {
    const float* x    = (const float*)d_in[0];
    const int*   ei   = (const int*)d_in[1];      // [2][E]: src then dst
    const float* W0l  = (const float*)d_in[3];
    const float* W0r  = (const float*)d_in[4];
    const float* a0   = (const float*)d_in[5];
    const float* Wres0= (const float*)d_in[6];
    const float* Wl   = (const float*)d_in[7];    // [2][128][128]
    const float* Wr   = (const float*)d_in[8];
    const float* att  = (const float*)d_in[9];    // [2][4][32]
    const float* Wh1  = (const float*)d_in[10];
    const float* bh1  = (const float*)d_in[11];
    const float* Wh2  = (const float*)d_in[12];
    const float* bh2  = (const float*)d_in[13];
    float* out = (float*)d_out;

    const int* src = ei;
    const int* dst = ei + EE;

    // workspace: emb | ptr | ptrw | csr | whi | wlo | (256B-aligned) bufA | bufB | bufC
    char* wsb = (char*)d_ws;
    float* emb = (float*)wsb;                               // [NN][128]
    size_t off = (size_t)NN * HID * 4;
    int* ptr  = (int*)(wsb + off);  off += (NN + 1) * 4;    // [NN+1]
    int* ptrw = (int*)(wsb + off);  off += NN * 4;          // [NN]
    int* csr  = (int*)(wsb + off);  off += (size_t)EE * 4;  // [EE]
    off = (off + 255) & ~(size_t)255;
    unsigned short* whi = (unsigned short*)(wsb + off); off += 5 * 16384 * 2;  // 160 KB
    unsigned short* wlo = (unsigned short*)(wsb + off); off += 5 * 16384 * 2;  // 160 KB
    off = (off + 255) & ~(size_t)255;
    size_t fixedBytes = off;

    // ws-adaptive pass sizing: k views per pass, k in {4,2,1}
    int k = 4;
    while (k > 1 && fixedBytes + 3ull * k * NN * HID * 4 > ws_size) k >>= 1;
    long K = (long)k * NN;           // rows per pass
    int npass = 4 / k;
    int gvPerXcd = (int)(K / 1024) / 8;   // graph-view chunks per XCD

    float* bufA = (float*)(wsb + off);            // [K][128]
    float* bufB = bufA + K * HID;                 // [K][128]
    float* bufC = bufB + K * HID;                 // [K][128]

    // --- CSR build (shared by all views/layers) + weight split ---
    hipMemsetAsync(ptrw, 0, NN * sizeof(int), stream);
    count_kernel<<<EE / 256, 256, 0, stream>>>(dst, ptrw);
    scan_kernel<<<1, 1024, 0, stream>>>(ptrw, ptr);
    scatter_kernel<<<EE / 256, 256, 0, stream>>>(src, dst, ptrw, csr);
    wsplit_kernel<<<dim3(8, 5), 256, 0, stream>>>(Wl, Wr, Wh1, whi, wlo);

    // --- emb = 0 ---
    hipMemsetAsync(emb, 0, (size_t)NN * HID * sizeof(float), stream);

    for (int p = 0; p < npass; p++) {
        int viewBase = p * k;
        // layer 0: hl->A, hr->B, hres->C;  attn0 (res=C) -> B (h0)
        l0_kernel<<<K / L0T, 256, 0, stream>>>(x, W0l, W0r, Wres0,
                                               bufA, bufB, bufC, viewBase);
        attn_kernel<<<K / 4, 256, 0, stream>>>(bufA, bufB, bufC, ptr, csr, a0, bufB, 1, gvPerXcd);
        // layer 1: gemm B->(A=hl via Wl0, C=hr via Wr0);  attn1 (res=B) -> C (h1)
        gemm_mfma<<<dim3(K / 128, 1, 2), 256, 0, stream>>>(bufB, whi, wlo, 0, 1,
                                                           bufA, bufC, nullptr, 0);
        attn_kernel<<<K / 4, 256, 0, stream>>>(bufA, bufC, bufB, ptr, csr, att, bufC, 1, gvPerXcd);
        // layer 2: gemm C->(A=hl via Wl1, B=hr via Wr1);  attn2 (res=C, no act) -> B (h2)
        gemm_mfma<<<dim3(K / 128, 1, 2), 256, 0, stream>>>(bufC, whi, wlo, 2, 3,
                                                           bufA, bufB, nullptr, 0);
        attn_kernel<<<K / 4, 256, 0, stream>>>(bufA, bufB, bufC, ptr, csr, att + HID, bufB, 0, gvPerXcd);
        // accumulate mean over views
        acc_kernel<<<NN * 32 / 256, 256, 0, stream>>>(bufB, emb, k);
    }

    // --- head: z = relu(emb@Wh1+bh1) -> bufA;  logits(bufA) -> out ---
    gemm_mfma<<<dim3(NN / 128, 1, 1), 256, 0, stream>>>(emb, whi, wlo, 4, 4,
                                                        bufA, bufA, bh1, 1);
    logits_kernel<<<NN * 64 / 256, 256, 0, stream>>>(bufA, Wh2, bh2, out);
}